// Round 1
// baseline (1084.119 us; speedup 1.0000x reference)
//
#include <hip/hip_runtime.h>
#include <hip/hip_bf16.h>
#include <math.h>

#define B_ 8
#define P_ 24
#define N_ 1024
#define C_ 16
#define D_ 256
#define K_ 13

// workspace offsets (in floats)
#define OFF_SM   0          // spatial_mean: 192*16
#define OFF_DL   4096       // d_lag: 8*4*24
#define OFF_ATT  8192       // att: 8*24
#define OFF_TE   12288      // te_fold: 192*256 (time_emb + in_proj_b)
#define OFF_FTR  65536      // Fte_re: 8*13*256
#define OFF_FTI  94208      // Fte_im
#define OFF_ZWC  122880     // zw_const: 8*256
#define OFF_AB   126976     // fused A/B: 13*32*256
#define OFF_C1   237568     // c1: 8*13*256
#define OFF_BC   266240     // bias_comb partials: 13*256
#define OFF_DD   270336     // D: 13*256*256
#define OFF_XC   1126400    // Xhat re+im: 8*13*1024*32
#define OFF_XW   4538368    // xw: 8*1024*16
#define OFF_P1H  4673536    // p1 (bf16): 8*13*1024*256 ushorts

__device__ __forceinline__ float gelu_f(float v) {
    return 0.5f * v * (1.0f + erff(v * 0.70710678118654752440f));
}
__device__ __forceinline__ float softplus_f(float z) {
    return fmaxf(z, 0.0f) + log1pf(expf(-fabsf(z)));
}
__device__ void sort24(float* a) {
    for (int i = 1; i < 24; i++) {
        float key = a[i];
        int j = i - 1;
        while (j >= 0 && a[j] > key) { a[j + 1] = a[j]; j--; }
        a[j + 1] = key;
    }
}

// ---- K1: spatial mean of x over N per (b,t) ----
__global__ void k_spatial_mean(const float* __restrict__ x, float* __restrict__ ws) {
    int bt = blockIdx.x;
    int tid = threadIdx.x;
    int c = tid & 15, ns = tid >> 4;
    const float* xp = x + (long)bt * (N_ * C_);
    float s = 0.f;
    for (int n = ns; n < N_; n += 16) s += xp[n * C_ + c];
    __shared__ float lds[256];
    lds[tid] = s;
    __syncthreads();
    for (int st = 128; st >= 16; st >>= 1) {
        if (tid < st) lds[tid] += lds[tid + st];
        __syncthreads();
    }
    if (tid < 16) ws[OFF_SM + bt * 16 + tid] = lds[tid] * (1.0f / 1024.0f);
}

// ---- K2: lag distances ----
__device__ __forceinline__ float xr_at(const float* xp, int t, int idx) {
    float xt = xp[(long)t * (N_ * C_) + idx];
    if (t == 0) return 0.f;
    if (t == 1) return xt - xp[idx];
    float a = xp[(long)(t - 1) * (N_ * C_) + idx];
    float b = xp[(long)(t - 2) * (N_ * C_) + idx];
    return xt - (xt + a + b) / 3.0f;
}
__global__ void k_lag_dist(const float* __restrict__ x, float* __restrict__ ws) {
    int t = blockIdx.x, li = blockIdx.y, b = blockIdx.z;
    const int lags[4] = {1, 2, 4, 6};
    int lag = lags[li];
    int tid = threadIdx.x;
    __shared__ float lds[256];
    float out = 0.f;
    if (t >= lag) {
        const float* xp = x + (long)b * P_ * N_ * C_;
        float s = 0.f;
        for (int idx = tid; idx < N_ * C_; idx += 256)
            s += fabsf(xr_at(xp, t, idx) - xr_at(xp, t - lag, idx));
        lds[tid] = s;
        __syncthreads();
        for (int st = 128; st > 0; st >>= 1) {
            if (tid < st) lds[tid] += lds[tid + st];
            __syncthreads();
        }
        out = lds[0] * (1.0f / (N_ * C_));
    }
    if (tid == 0) ws[OFF_DL + (b * 4 + li) * P_ + t] = out;
}

// ---- K3: gating -> att ----
__global__ void k_gating(const float* __restrict__ pool_param, float* __restrict__ ws) {
    int b = threadIdx.x;
    if (b >= B_) return;
    float g[P_];
    for (int t = 0; t < P_; t++) g[t] = 0.f;
    for (int li = 0; li < 4; li++) {
        float d[P_], s[P_];
        for (int t = 0; t < P_; t++) d[t] = ws[OFF_DL + (b * 4 + li) * P_ + t];
        for (int t = 0; t < P_; t++) s[t] = d[t];
        sort24(s);
        float med = s[11];
        for (int t = 0; t < P_; t++) s[t] = fabsf(d[t] - med);
        sort24(s);
        float mad = s[11];
        float denom = mad * 1.4826f + 1e-6f;
        for (int t = 0; t < P_; t++) g[t] += 0.25f * softplus_f((d[t] - med) / denom);
    }
    float c = g[0];
    float g2[P_];
    g2[0] = g[0];
    for (int t = 1; t < P_; t++) { c = 0.6f * c + 0.4f * g[t]; g2[t] = c; }
    float mean = 0.f;
    for (int t = 0; t < P_; t++) mean += g2[t];
    mean *= (1.0f / P_);
    float gate[P_];
    for (int t = 0; t < P_; t++) gate[t] = 1.0f / (1.0f + expf(-1.5f * (g2[t] - mean)));
    float m = -1e30f;
    for (int t = 0; t < P_; t++) m = fmaxf(m, pool_param[t]);
    float ba[P_], ssum = 0.f;
    for (int t = 0; t < P_; t++) { ba[t] = expf(pool_param[t] - m); ssum += ba[t]; }
    for (int t = 0; t < P_; t++) ba[t] /= ssum;
    float ar[P_];
    float m2 = -1e30f;
    for (int t = 0; t < P_; t++) { ar[t] = ba[t] * (1.0f + gate[t]); m2 = fmaxf(m2, ar[t]); }
    float s2 = 0.f;
    for (int t = 0; t < P_; t++) { ar[t] = expf(ar[t] - m2); s2 += ar[t]; }
    for (int t = 0; t < P_; t++) ws[OFF_ATT + b * P_ + t] = ar[t] / s2;
}

// ---- K4: time_emb (+ in_proj_b folded) ----
__global__ void k_time_emb(const float* __restrict__ pe_w1, const float* __restrict__ pe_b1,
                           const float* __restrict__ pe_w2, const float* __restrict__ pe_b2,
                           const float* __restrict__ noise_w, const float* __restrict__ noise_b,
                           const float* __restrict__ in_proj_b, float* __restrict__ ws) {
    int bt = blockIdx.x;
    int t = bt % P_;
    int tid = threadIdx.x;  // 128
    int k = tid >> 6, o = tid & 63;
    __shared__ float p1e[128];
    float period = (k == 0) ? 24.0f : 72.0f;
    float ph = 6.283185307179586f * (float)t / period;
    float sv = sinf(ph), cv = cosf(ph);
    float v = sv * pe_w1[(k * 2 + 0) * 64 + o] + cv * pe_w1[(k * 2 + 1) * 64 + o] + pe_b1[k * 64 + o];
    p1e[tid] = gelu_f(v);
    __syncthreads();
    float acc = pe_b2[k * 64 + o];
    for (int i = 0; i < 64; i++) acc += p1e[k * 64 + i] * pe_w2[(k * 64 + i) * 64 + o];
    ws[OFF_TE + bt * D_ + tid] = acc + in_proj_b[tid];
    float nacc = noise_b[tid];
    for (int c = 0; c < C_; c++) nacc += ws[OFF_SM + bt * C_ + c] * noise_w[c * 128 + tid];
    ws[OFF_TE + bt * D_ + 128 + tid] = nacc + in_proj_b[128 + tid];
}

// ---- K5: DFT of te_fold, att-weighted te, time_vec ----
__global__ void k_te_reduce(const float* __restrict__ in_proj_b, float* __restrict__ ws,
                            float* __restrict__ out) {
    int b = blockIdx.x;
    int tid = threadIdx.x;  // 256 = channel
    __shared__ float ct[K_ * P_], st[K_ * P_], attl[P_];
    for (int i = tid; i < K_ * P_; i += 256) {
        int k = i / P_, t = i % P_;
        int r = (k * t) % P_;
        float ph = 6.283185307179586f * (float)r / (float)P_;
        ct[i] = cosf(ph);
        st[i] = sinf(ph);
    }
    if (tid < P_) attl[tid] = ws[OFF_ATT + b * P_ + tid];
    __syncthreads();
    float fre[K_], fim[K_];
    #pragma unroll
    for (int k = 0; k < K_; k++) { fre[k] = 0.f; fim[k] = 0.f; }
    float sm = 0.f, sa = 0.f;
    for (int t = 0; t < P_; t++) {
        float v = ws[OFF_TE + (b * P_ + t) * D_ + tid];
        sm += v;
        sa += attl[t] * v;
        #pragma unroll
        for (int k = 0; k < K_; k++) {
            fre[k] += ct[k * P_ + t] * v;
            fim[k] -= st[k * P_ + t] * v;
        }
    }
    out[2097152 + b * D_ + tid] = sm * (1.0f / P_) - in_proj_b[tid];
    ws[OFF_ZWC + b * D_ + tid] = sa;
    #pragma unroll
    for (int k = 0; k < K_; k++) {
        ws[OFF_FTR + (b * K_ + k) * D_ + tid] = fre[k];
        ws[OFF_FTI + (b * K_ + k) * D_ + tid] = fim[k];
    }
}

// ---- K6a: A_k = W_in @ W1re_k, B_k = W_in @ W1im_k ----
__global__ void k_prep_ab(const float* __restrict__ in_proj_w, const float* __restrict__ sfe_w1,
                          float* __restrict__ ws) {
    int k = blockIdx.x;
    int o = threadIdx.x;
    float accA[C_], accB[C_];
    #pragma unroll
    for (int c = 0; c < C_; c++) { accA[c] = 0.f; accB[c] = 0.f; }
    const float* w1r = sfe_w1 + (long)k * 512 * 256;
    const float* w1i = w1r + 256 * 256;
    for (int e = 0; e < 256; e++) {
        float vr = w1r[e * 256 + o];
        float vi = w1i[e * 256 + o];
        #pragma unroll
        for (int c = 0; c < C_; c++) {
            float w = in_proj_w[c * 256 + e];
            accA[c] += w * vr;
            accB[c] += w * vi;
        }
    }
    for (int c = 0; c < C_; c++) {
        ws[OFF_AB + (k * 32 + c) * 256 + o] = accA[c];
        ws[OFF_AB + (k * 32 + 16 + c) * 256 + o] = accB[c];
    }
}

// ---- K6b: D_k = sfe_w2[k] @ comb_w1[k-block] ----
__global__ void k_prep_d(const float* __restrict__ sfe_w2, const float* __restrict__ comb_w1,
                         float* __restrict__ ws) {
    int itile = blockIdx.x, k = blockIdx.y;
    int q = threadIdx.x;
    float acc[16];
    #pragma unroll
    for (int i = 0; i < 16; i++) acc[i] = 0.f;
    for (int o = 0; o < 256; o++) {
        float cw = comb_w1[((k * 256 + o) << 8) + q];
        #pragma unroll
        for (int i2 = 0; i2 < 16; i2++)
            acc[i2] += sfe_w2[(k * 256 + itile * 16 + i2) * 256 + o] * cw;
    }
    for (int i2 = 0; i2 < 16; i2++)
        ws[OFF_DD + ((k * 256 + itile * 16 + i2) << 8) + q] = acc[i2];
}

// ---- K6c: c1[b,k,:] = Fte_re@W1re + Fte_im@W1im + sfe_b1 ----
__global__ void k_prep_c1(const float* __restrict__ sfe_w1, const float* __restrict__ sfe_b1,
                          float* __restrict__ ws) {
    int k = blockIdx.x, b = blockIdx.y;
    int o = threadIdx.x;
    float acc = sfe_b1[k * 256 + o];
    const float* w1 = sfe_w1 + (long)k * 512 * 256;
    const float* fr = ws + OFF_FTR + (b * K_ + k) * D_;
    const float* fi = ws + OFF_FTI + (b * K_ + k) * D_;
    for (int c = 0; c < 256; c++)
        acc += fr[c] * w1[c * 256 + o] + fi[c] * w1[(256 + c) * 256 + o];
    ws[OFF_C1 + (b * K_ + k) * D_ + o] = acc;
}

// ---- K6d: bias_comb partial per k ----
__global__ void k_prep_bias(const float* __restrict__ sfe_b2, const float* __restrict__ comb_w1,
                            float* __restrict__ ws) {
    int k = blockIdx.x;
    int q = threadIdx.x;
    float acc = 0.f;
    for (int o = 0; o < 256; o++)
        acc += sfe_b2[k * 256 + o] * comb_w1[((k * 256 + o) << 8) + q];
    ws[OFF_BC + k * 256 + q] = acc;
}

// ---- K7: Xhat (DFT of x over t) + att-weighted x ----
__global__ void k_xhat(const float* __restrict__ x, float* __restrict__ ws) {
    int ntile = blockIdx.x, b = blockIdx.y;
    int tid = threadIdx.x;
    int n = ntile * 16 + (tid >> 4), c = tid & 15;
    __shared__ float ct[K_ * P_], st[K_ * P_], attl[P_];
    for (int i = tid; i < K_ * P_; i += 256) {
        int k = i / P_, t = i % P_;
        int r = (k * t) % P_;
        float ph = 6.283185307179586f * (float)r / (float)P_;
        ct[i] = cosf(ph);
        st[i] = sinf(ph);
    }
    if (tid < P_) attl[tid] = ws[OFF_ATT + b * P_ + tid];
    __syncthreads();
    float re[K_], im[K_], xwa = 0.f;
    #pragma unroll
    for (int k = 0; k < K_; k++) { re[k] = 0.f; im[k] = 0.f; }
    for (int t = 0; t < P_; t++) {
        float v = x[((long)(b * P_ + t) * N_ + n) * C_ + c];
        xwa += attl[t] * v;
        #pragma unroll
        for (int k = 0; k < K_; k++) {
            re[k] += ct[k * P_ + t] * v;
            im[k] -= st[k * P_ + t] * v;
        }
    }
    #pragma unroll
    for (int k = 0; k < K_; k++) {
        long xb = OFF_XC + ((long)(b * K_ + k) * N_ + n) * 32;
        ws[xb + c] = re[k];
        ws[xb + 16 + c] = im[k];
    }
    ws[OFF_XW + ((long)b * N_ + n) * C_ + c] = xwa;
}

// ---- K8: p1 = gelu(Xc @ AB_k + c1), stored bf16 ----
__global__ void k_p1(const float* __restrict__ ws, __hip_bfloat16* __restrict__ p1h) {
    int ntile = blockIdx.x, k = blockIdx.y, b = blockIdx.z;
    int o = threadIdx.x;
    __shared__ float xs[64 * 32];
    long xbase = OFF_XC + ((long)(b * K_ + k) * N_ + ntile * 64) * 32;
    for (int j = 0; j < 8; j++) xs[j * 256 + o] = ws[xbase + j * 256 + o];
    float ab[32];
    #pragma unroll
    for (int e = 0; e < 32; e++) ab[e] = ws[OFF_AB + (k * 32 + e) * 256 + o];
    float c1v = ws[OFF_C1 + (b * K_ + k) * D_ + o];
    __syncthreads();
    long pbase = ((long)(b * K_ + k) * N_ + ntile * 64) * 256;
    for (int np = 0; np < 64; np++) {
        const float4* xrow = (const float4*)&xs[np * 32];
        float acc = c1v;
        #pragma unroll
        for (int e4 = 0; e4 < 8; e4++) {
            float4 p = xrow[e4];
            acc += p.x * ab[e4 * 4] + p.y * ab[e4 * 4 + 1] + p.z * ab[e4 * 4 + 2] + p.w * ab[e4 * 4 + 3];
        }
        acc = gelu_f(acc);
        p1h[pbase + np * 256 + o] = __float2bfloat16(acc);
    }
}

// ---- K9: acc = sum_k p1@D_k ; h_freq = gelu(acc+bias)@W2+b2 ; z ----
__global__ void k_final(const float* __restrict__ ws, const __hip_bfloat16* __restrict__ p1h,
                        const float* __restrict__ comb_w2, const float* __restrict__ comb_b2,
                        const float* __restrict__ comb_b1, const float* __restrict__ in_proj_w,
                        float* __restrict__ out) {
    int ntile = blockIdx.x, b = blockIdx.y;  // 64 x 8
    int tid = threadIdx.x;
    int qt = tid & 63, nt = tid >> 6;
    int q0 = qt * 4, nr0 = nt * 4;
    int n0 = ntile * 16;
    __shared__ float tile[16 * 256];
    __shared__ float xwl[16 * 16];
    xwl[tid] = ws[OFF_XW + ((long)b * N_ + n0) * C_ + tid];
    float acc[4][4];
    #pragma unroll
    for (int j = 0; j < 4; j++)
        for (int qq = 0; qq < 4; qq++) acc[j][qq] = 0.f;
    const float* Dp = ws + OFF_DD;
    for (int k = 0; k < K_; k++) {
        __syncthreads();
        long pbase = ((long)(b * K_ + k) * N_ + n0) * 256;
        for (int j = 0; j < 16; j++)
            tile[j * 256 + tid] = __bfloat162float(p1h[pbase + j * 256 + tid]);
        __syncthreads();
        #pragma unroll 4
        for (int i = 0; i < 256; i++) {
            const float4 dv = *(const float4*)&Dp[((k * 256 + i) << 8) + q0];
            #pragma unroll
            for (int j = 0; j < 4; j++) {
                float a = tile[(nr0 + j) * 256 + i];
                acc[j][0] += a * dv.x;
                acc[j][1] += a * dv.y;
                acc[j][2] += a * dv.z;
                acc[j][3] += a * dv.w;
            }
        }
    }
    __syncthreads();
    float4 bc = *(const float4*)&comb_b1[q0];
    #pragma unroll
    for (int k = 0; k < K_; k++) {
        const float4 pp = *(const float4*)&ws[OFF_BC + k * 256 + q0];
        bc.x += pp.x; bc.y += pp.y; bc.z += pp.z; bc.w += pp.w;
    }
    for (int j = 0; j < 4; j++) {
        float4 pv;
        pv.x = gelu_f(acc[j][0] + bc.x);
        pv.y = gelu_f(acc[j][1] + bc.y);
        pv.z = gelu_f(acc[j][2] + bc.z);
        pv.w = gelu_f(acc[j][3] + bc.w);
        *(float4*)&tile[(nr0 + j) * 256 + q0] = pv;
    }
    __syncthreads();
    float hf[4][4];
    #pragma unroll
    for (int j = 0; j < 4; j++)
        for (int qq = 0; qq < 4; qq++) hf[j][qq] = 0.f;
    #pragma unroll 4
    for (int i = 0; i < 256; i++) {
        const float4 w2 = *(const float4*)&comb_w2[(i << 8) + q0];
        #pragma unroll
        for (int j = 0; j < 4; j++) {
            float a = tile[(nr0 + j) * 256 + i];
            hf[j][0] += a * w2.x;
            hf[j][1] += a * w2.y;
            hf[j][2] += a * w2.z;
            hf[j][3] += a * w2.w;
        }
    }
    const float4 cb2 = *(const float4*)&comb_b2[q0];
    const float4 zc = *(const float4*)&ws[OFF_ZWC + b * D_ + q0];
    for (int j = 0; j < 4; j++) {
        float4 zz;
        zz.x = zc.x + 0.3f * (hf[j][0] + cb2.x);
        zz.y = zc.y + 0.3f * (hf[j][1] + cb2.y);
        zz.z = zc.z + 0.3f * (hf[j][2] + cb2.z);
        zz.w = zc.w + 0.3f * (hf[j][3] + cb2.w);
        #pragma unroll
        for (int c = 0; c < C_; c++) {
            float xv = xwl[(nr0 + j) * C_ + c];
            const float4 wv = *(const float4*)&in_proj_w[(c << 8) + q0];
            zz.x += xv * wv.x;
            zz.y += xv * wv.y;
            zz.z += xv * wv.z;
            zz.w += xv * wv.w;
        }
        *(float4*)&out[((long)(b * N_ + n0 + nr0 + j) << 8) + q0] = zz;
    }
}

extern "C" void kernel_launch(void* const* d_in, const int* in_sizes, int n_in,
                              void* d_out, int out_size, void* d_ws, size_t ws_size,
                              hipStream_t stream) {
    const float* x = (const float*)d_in[0];
    const float* in_proj_w = (const float*)d_in[1];
    const float* in_proj_b = (const float*)d_in[2];
    const float* pe_w1 = (const float*)d_in[3];
    const float* pe_b1 = (const float*)d_in[4];
    const float* pe_w2 = (const float*)d_in[5];
    const float* pe_b2 = (const float*)d_in[6];
    const float* noise_w = (const float*)d_in[7];
    const float* noise_b = (const float*)d_in[8];
    const float* sfe_w1 = (const float*)d_in[9];
    const float* sfe_b1 = (const float*)d_in[10];
    const float* sfe_w2 = (const float*)d_in[11];
    const float* sfe_b2 = (const float*)d_in[12];
    const float* comb_w1 = (const float*)d_in[13];
    const float* comb_b1 = (const float*)d_in[14];
    const float* comb_w2 = (const float*)d_in[15];
    const float* comb_b2 = (const float*)d_in[16];
    const float* pool_param = (const float*)d_in[17];
    float* ws = (float*)d_ws;
    __hip_bfloat16* p1h = (__hip_bfloat16*)(ws + OFF_P1H);
    float* out = (float*)d_out;

    hipLaunchKernelGGL(k_spatial_mean, dim3(192), dim3(256), 0, stream, x, ws);
    hipLaunchKernelGGL(k_lag_dist, dim3(24, 4, 8), dim3(256), 0, stream, x, ws);
    hipLaunchKernelGGL(k_gating, dim3(1), dim3(64), 0, stream, pool_param, ws);
    hipLaunchKernelGGL(k_time_emb, dim3(192), dim3(128), 0, stream,
                       pe_w1, pe_b1, pe_w2, pe_b2, noise_w, noise_b, in_proj_b, ws);
    hipLaunchKernelGGL(k_te_reduce, dim3(8), dim3(256), 0, stream, in_proj_b, ws, out);
    hipLaunchKernelGGL(k_prep_ab, dim3(13), dim3(256), 0, stream, in_proj_w, sfe_w1, ws);
    hipLaunchKernelGGL(k_prep_d, dim3(16, 13), dim3(256), 0, stream, sfe_w2, comb_w1, ws);
    hipLaunchKernelGGL(k_prep_bias, dim3(13), dim3(256), 0, stream, sfe_b2, comb_w1, ws);
    hipLaunchKernelGGL(k_prep_c1, dim3(13, 8), dim3(256), 0, stream, sfe_w1, sfe_b1, ws);
    hipLaunchKernelGGL(k_xhat, dim3(64, 8), dim3(256), 0, stream, x, ws);
    hipLaunchKernelGGL(k_p1, dim3(16, 13, 8), dim3(256), 0, stream, ws, p1h);
    hipLaunchKernelGGL(k_final, dim3(64, 8), dim3(256), 0, stream,
                       ws, p1h, comb_w2, comb_b2, comb_b1, in_proj_w, out);
}

// Round 2
// 732.065 us; speedup vs baseline: 1.4809x; 1.4809x over previous
//
#include <hip/hip_runtime.h>
#include <hip/hip_bf16.h>
#include <math.h>

#define B_ 8
#define P_ 24
#define N_ 1024
#define C_ 16
#define D_ 256
#define K_ 13

// workspace offsets (in floats)
#define OFF_SM   0          // spatial_mean: 192*16
#define OFF_DL   4096       // d_lag: 8*4*24
#define OFF_ATT  8192       // att: 8*24
#define OFF_TE   12288      // te_fold: 192*256 (time_emb + in_proj_b)
#define OFF_FTR  65536      // Fte_re: 8*13*256
#define OFF_FTI  94208      // Fte_im
#define OFF_ZWC  122880     // zw_const: 8*256
#define OFF_AB   126976     // fused A/B: 13*32*256
#define OFF_C1   237568     // c1: 8*13*256
#define OFF_BC   266240     // bias_comb partials: 13*256
#define OFF_DD   270336     // D: 13*256*256
#define OFF_XC   1126400    // Xhat re+im: 8*13*1024*32
#define OFF_XW   4538368    // xw: 8*1024*16
#define OFF_P1H  4673536    // p1 (bf16): 8*13*1024*256 ushorts

__device__ __forceinline__ float gelu_f(float v) {
    return 0.5f * v * (1.0f + erff(v * 0.70710678118654752440f));
}
__device__ __forceinline__ float softplus_f(float z) {
    return fmaxf(z, 0.0f) + log1pf(expf(-fabsf(z)));
}

// ---- K1: spatial mean of x over N per (b,t) ----
__global__ void k_spatial_mean(const float* __restrict__ x, float* __restrict__ ws) {
    int bt = blockIdx.x;
    int tid = threadIdx.x;
    int c = tid & 15, ns = tid >> 4;
    const float* xp = x + (long)bt * (N_ * C_);
    float s = 0.f;
    for (int n = ns; n < N_; n += 16) s += xp[n * C_ + c];
    __shared__ float lds[256];
    lds[tid] = s;
    __syncthreads();
    for (int st = 128; st >= 16; st >>= 1) {
        if (tid < st) lds[tid] += lds[tid + st];
        __syncthreads();
    }
    if (tid < 16) ws[OFF_SM + bt * 16 + tid] = lds[tid] * (1.0f / 1024.0f);
}

// ---- K2: lag distances ----
__device__ __forceinline__ float xr_at(const float* xp, int t, int idx) {
    float xt = xp[(long)t * (N_ * C_) + idx];
    if (t == 0) return 0.f;
    if (t == 1) return xt - xp[idx];
    float a = xp[(long)(t - 1) * (N_ * C_) + idx];
    float b = xp[(long)(t - 2) * (N_ * C_) + idx];
    return xt - (xt + a + b) / 3.0f;
}
__global__ void k_lag_dist(const float* __restrict__ x, float* __restrict__ ws) {
    int t = blockIdx.x, li = blockIdx.y, b = blockIdx.z;
    const int lags[4] = {1, 2, 4, 6};
    int lag = lags[li];
    int tid = threadIdx.x;
    __shared__ float lds[256];
    float out = 0.f;
    if (t >= lag) {
        const float* xp = x + (long)b * P_ * N_ * C_;
        float s = 0.f;
        for (int idx = tid; idx < N_ * C_; idx += 256)
            s += fabsf(xr_at(xp, t, idx) - xr_at(xp, t - lag, idx));
        lds[tid] = s;
        __syncthreads();
        for (int st = 128; st > 0; st >>= 1) {
            if (tid < st) lds[tid] += lds[tid + st];
            __syncthreads();
        }
        out = lds[0] * (1.0f / (N_ * C_));
    }
    if (tid == 0) ws[OFF_DL + (b * 4 + li) * P_ + t] = out;
}

// ---- K3: gating -> att  (rank-select median, all-LDS, 8 blocks x 128 thr) ----
__global__ void k_gating(const float* __restrict__ pool_param, float* __restrict__ ws) {
    int b = blockIdx.x;
    int tid = threadIdx.x;  // 128
    int li = tid / P_, t = tid - li * P_;
    bool active = tid < 4 * P_;
    __shared__ float d[4][P_], ad[4][P_], med[4], mad[4], g[P_], gbuf[P_];
    if (active) d[li][t] = ws[OFF_DL + (b * 4 + li) * P_ + t];
    __syncthreads();
    if (active) {
        float v = d[li][t];
        int rank = 0;
        #pragma unroll
        for (int j = 0; j < P_; j++) {
            float dj = d[li][j];
            rank += (dj < v || (dj == v && j < t)) ? 1 : 0;
        }
        if (rank == 11) med[li] = v;
    }
    __syncthreads();
    if (active) ad[li][t] = fabsf(d[li][t] - med[li]);
    __syncthreads();
    if (active) {
        float v = ad[li][t];
        int rank = 0;
        #pragma unroll
        for (int j = 0; j < P_; j++) {
            float dj = ad[li][j];
            rank += (dj < v || (dj == v && j < t)) ? 1 : 0;
        }
        if (rank == 11) mad[li] = v;
    }
    __syncthreads();
    if (active) {
        float z = (d[li][t] - med[li]) / (mad[li] * 1.4826f + 1e-6f);
        ad[li][t] = softplus_f(z);
    }
    __syncthreads();
    if (tid < P_) g[tid] = 0.25f * (ad[0][tid] + ad[1][tid] + ad[2][tid] + ad[3][tid]);
    __syncthreads();
    if (tid == 0) {
        float c = g[0];
        gbuf[0] = g[0];
        for (int tt = 1; tt < P_; tt++) { c = 0.6f * c + 0.4f * g[tt]; gbuf[tt] = c; }
        float mean = 0.f;
        for (int tt = 0; tt < P_; tt++) mean += gbuf[tt];
        mean *= (1.0f / P_);
        float gate[P_];
        #pragma unroll
        for (int tt = 0; tt < P_; tt++) gate[tt] = 1.0f / (1.0f + expf(-1.5f * (gbuf[tt] - mean)));
        float m = -1e30f;
        float pp[P_];
        #pragma unroll
        for (int tt = 0; tt < P_; tt++) { pp[tt] = pool_param[tt]; m = fmaxf(m, pp[tt]); }
        float ssum = 0.f;
        #pragma unroll
        for (int tt = 0; tt < P_; tt++) { pp[tt] = expf(pp[tt] - m); ssum += pp[tt]; }
        float m2 = -1e30f;
        #pragma unroll
        for (int tt = 0; tt < P_; tt++) { pp[tt] = (pp[tt] / ssum) * (1.0f + gate[tt]); m2 = fmaxf(m2, pp[tt]); }
        float s2 = 0.f;
        #pragma unroll
        for (int tt = 0; tt < P_; tt++) { pp[tt] = expf(pp[tt] - m2); s2 += pp[tt]; }
        #pragma unroll
        for (int tt = 0; tt < P_; tt++) ws[OFF_ATT + b * P_ + tt] = pp[tt] / s2;
    }
}

// ---- K4: time_emb (+ in_proj_b folded) ----
__global__ void k_time_emb(const float* __restrict__ pe_w1, const float* __restrict__ pe_b1,
                           const float* __restrict__ pe_w2, const float* __restrict__ pe_b2,
                           const float* __restrict__ noise_w, const float* __restrict__ noise_b,
                           const float* __restrict__ in_proj_b, float* __restrict__ ws) {
    int bt = blockIdx.x;
    int t = bt % P_;
    int tid = threadIdx.x;  // 128
    int k = tid >> 6, o = tid & 63;
    __shared__ float p1e[128];
    float period = (k == 0) ? 24.0f : 72.0f;
    float ph = 6.283185307179586f * (float)t / period;
    float sv = sinf(ph), cv = cosf(ph);
    float v = sv * pe_w1[(k * 2 + 0) * 64 + o] + cv * pe_w1[(k * 2 + 1) * 64 + o] + pe_b1[k * 64 + o];
    p1e[tid] = gelu_f(v);
    __syncthreads();
    float acc = pe_b2[k * 64 + o];
    for (int i = 0; i < 64; i++) acc += p1e[k * 64 + i] * pe_w2[(k * 64 + i) * 64 + o];
    ws[OFF_TE + bt * D_ + tid] = acc + in_proj_b[tid];
    float nacc = noise_b[tid];
    for (int c = 0; c < C_; c++) nacc += ws[OFF_SM + bt * C_ + c] * noise_w[c * 128 + tid];
    ws[OFF_TE + bt * D_ + 128 + tid] = nacc + in_proj_b[128 + tid];
}

// ---- K5: DFT of te_fold, att-weighted te, time_vec ----
__global__ void k_te_reduce(const float* __restrict__ in_proj_b, float* __restrict__ ws,
                            float* __restrict__ out) {
    int b = blockIdx.x;
    int tid = threadIdx.x;  // 256 = channel
    __shared__ float ct[K_ * P_], st[K_ * P_], attl[P_];
    for (int i = tid; i < K_ * P_; i += 256) {
        int k = i / P_, t = i % P_;
        int r = (k * t) % P_;
        float ph = 6.283185307179586f * (float)r / (float)P_;
        ct[i] = cosf(ph);
        st[i] = sinf(ph);
    }
    if (tid < P_) attl[tid] = ws[OFF_ATT + b * P_ + tid];
    __syncthreads();
    float fre[K_], fim[K_];
    #pragma unroll
    for (int k = 0; k < K_; k++) { fre[k] = 0.f; fim[k] = 0.f; }
    float sm = 0.f, sa = 0.f;
    for (int t = 0; t < P_; t++) {
        float v = ws[OFF_TE + (b * P_ + t) * D_ + tid];
        sm += v;
        sa += attl[t] * v;
        #pragma unroll
        for (int k = 0; k < K_; k++) {
            fre[k] += ct[k * P_ + t] * v;
            fim[k] -= st[k * P_ + t] * v;
        }
    }
    out[2097152 + b * D_ + tid] = sm * (1.0f / P_) - in_proj_b[tid];
    ws[OFF_ZWC + b * D_ + tid] = sa;
    #pragma unroll
    for (int k = 0; k < K_; k++) {
        ws[OFF_FTR + (b * K_ + k) * D_ + tid] = fre[k];
        ws[OFF_FTI + (b * K_ + k) * D_ + tid] = fim[k];
    }
}

// ---- K6a: A_k = W_in @ W1re_k, B_k = W_in @ W1im_k ----
__global__ void k_prep_ab(const float* __restrict__ in_proj_w, const float* __restrict__ sfe_w1,
                          float* __restrict__ ws) {
    int k = blockIdx.x;
    int o = threadIdx.x;
    float accA[C_], accB[C_];
    #pragma unroll
    for (int c = 0; c < C_; c++) { accA[c] = 0.f; accB[c] = 0.f; }
    const float* w1r = sfe_w1 + (long)k * 512 * 256;
    const float* w1i = w1r + 256 * 256;
    for (int e = 0; e < 256; e++) {
        float vr = w1r[e * 256 + o];
        float vi = w1i[e * 256 + o];
        #pragma unroll
        for (int c = 0; c < C_; c++) {
            float w = in_proj_w[c * 256 + e];
            accA[c] += w * vr;
            accB[c] += w * vi;
        }
    }
    for (int c = 0; c < C_; c++) {
        ws[OFF_AB + (k * 32 + c) * 256 + o] = accA[c];
        ws[OFF_AB + (k * 32 + 16 + c) * 256 + o] = accB[c];
    }
}

// ---- K6b: D_k = sfe_w2[k] @ comb_w1[k-block] ----
__global__ void k_prep_d(const float* __restrict__ sfe_w2, const float* __restrict__ comb_w1,
                         float* __restrict__ ws) {
    int itile = blockIdx.x, k = blockIdx.y;
    int q = threadIdx.x;
    float acc[16];
    #pragma unroll
    for (int i = 0; i < 16; i++) acc[i] = 0.f;
    for (int o = 0; o < 256; o++) {
        float cw = comb_w1[((k * 256 + o) << 8) + q];
        #pragma unroll
        for (int i2 = 0; i2 < 16; i2++)
            acc[i2] += sfe_w2[(k * 256 + itile * 16 + i2) * 256 + o] * cw;
    }
    for (int i2 = 0; i2 < 16; i2++)
        ws[OFF_DD + ((k * 256 + itile * 16 + i2) << 8) + q] = acc[i2];
}

// ---- K6c: c1[b,k,:] = Fte_re@W1re + Fte_im@W1im + sfe_b1 ----
__global__ void k_prep_c1(const float* __restrict__ sfe_w1, const float* __restrict__ sfe_b1,
                          float* __restrict__ ws) {
    int k = blockIdx.x, b = blockIdx.y;
    int o = threadIdx.x;
    float acc = sfe_b1[k * 256 + o];
    const float* w1 = sfe_w1 + (long)k * 512 * 256;
    const float* fr = ws + OFF_FTR + (b * K_ + k) * D_;
    const float* fi = ws + OFF_FTI + (b * K_ + k) * D_;
    for (int c = 0; c < 256; c++)
        acc += fr[c] * w1[c * 256 + o] + fi[c] * w1[(256 + c) * 256 + o];
    ws[OFF_C1 + (b * K_ + k) * D_ + o] = acc;
}

// ---- K6d: bias_comb partial per k ----
__global__ void k_prep_bias(const float* __restrict__ sfe_b2, const float* __restrict__ comb_w1,
                            float* __restrict__ ws) {
    int k = blockIdx.x;
    int q = threadIdx.x;
    float acc = 0.f;
    for (int o = 0; o < 256; o++)
        acc += sfe_b2[k * 256 + o] * comb_w1[((k * 256 + o) << 8) + q];
    ws[OFF_BC + k * 256 + q] = acc;
}

// ---- K7: Xhat (DFT of x over t) + att-weighted x ----
__global__ void k_xhat(const float* __restrict__ x, float* __restrict__ ws) {
    int ntile = blockIdx.x, b = blockIdx.y;
    int tid = threadIdx.x;
    int n = ntile * 16 + (tid >> 4), c = tid & 15;
    __shared__ float ct[K_ * P_], st[K_ * P_], attl[P_];
    for (int i = tid; i < K_ * P_; i += 256) {
        int k = i / P_, t = i % P_;
        int r = (k * t) % P_;
        float ph = 6.283185307179586f * (float)r / (float)P_;
        ct[i] = cosf(ph);
        st[i] = sinf(ph);
    }
    if (tid < P_) attl[tid] = ws[OFF_ATT + b * P_ + tid];
    __syncthreads();
    float re[K_], im[K_], xwa = 0.f;
    #pragma unroll
    for (int k = 0; k < K_; k++) { re[k] = 0.f; im[k] = 0.f; }
    for (int t = 0; t < P_; t++) {
        float v = x[((long)(b * P_ + t) * N_ + n) * C_ + c];
        xwa += attl[t] * v;
        #pragma unroll
        for (int k = 0; k < K_; k++) {
            re[k] += ct[k * P_ + t] * v;
            im[k] -= st[k * P_ + t] * v;
        }
    }
    #pragma unroll
    for (int k = 0; k < K_; k++) {
        long xb = OFF_XC + ((long)(b * K_ + k) * N_ + n) * 32;
        ws[xb + c] = re[k];
        ws[xb + 16 + c] = im[k];
    }
    ws[OFF_XW + ((long)b * N_ + n) * C_ + c] = xwa;
}

// ---- K8: p1 = gelu(Xc @ AB_k + c1), stored bf16 ----
__global__ void k_p1(const float* __restrict__ ws, __hip_bfloat16* __restrict__ p1h) {
    int ntile = blockIdx.x, k = blockIdx.y, b = blockIdx.z;
    int o = threadIdx.x;
    __shared__ float xs[64 * 32];
    long xbase = OFF_XC + ((long)(b * K_ + k) * N_ + ntile * 64) * 32;
    for (int j = 0; j < 8; j++) xs[j * 256 + o] = ws[xbase + j * 256 + o];
    float ab[32];
    #pragma unroll
    for (int e = 0; e < 32; e++) ab[e] = ws[OFF_AB + (k * 32 + e) * 256 + o];
    float c1v = ws[OFF_C1 + (b * K_ + k) * D_ + o];
    __syncthreads();
    long pbase = ((long)(b * K_ + k) * N_ + ntile * 64) * 256;
    for (int np = 0; np < 64; np++) {
        const float4* xrow = (const float4*)&xs[np * 32];
        float acc = c1v;
        #pragma unroll
        for (int e4 = 0; e4 < 8; e4++) {
            float4 p = xrow[e4];
            acc += p.x * ab[e4 * 4] + p.y * ab[e4 * 4 + 1] + p.z * ab[e4 * 4 + 2] + p.w * ab[e4 * 4 + 3];
        }
        acc = gelu_f(acc);
        p1h[pbase + np * 256 + o] = __float2bfloat16(acc);
    }
}

// ---- K9: acc = sum_k p1@D_k ; h_freq = gelu(acc+bias)@W2+b2 ; z ----
__global__ void k_final(const float* __restrict__ ws, const __hip_bfloat16* __restrict__ p1h,
                        const float* __restrict__ comb_w2, const float* __restrict__ comb_b2,
                        const float* __restrict__ comb_b1, const float* __restrict__ in_proj_w,
                        float* __restrict__ out) {
    int ntile = blockIdx.x, b = blockIdx.y;  // 64 x 8
    int tid = threadIdx.x;
    int qt = tid & 63, nt = tid >> 6;
    int q0 = qt * 4, nr0 = nt * 4;
    int n0 = ntile * 16;
    __shared__ float tile[16 * 256];
    __shared__ float xwl[16 * 16];
    xwl[tid] = ws[OFF_XW + ((long)b * N_ + n0) * C_ + tid];
    float acc[4][4];
    #pragma unroll
    for (int j = 0; j < 4; j++)
        for (int qq = 0; qq < 4; qq++) acc[j][qq] = 0.f;
    const float* Dp = ws + OFF_DD;
    for (int k = 0; k < K_; k++) {
        __syncthreads();
        long pbase = ((long)(b * K_ + k) * N_ + n0) * 256;
        for (int j = 0; j < 16; j++)
            tile[j * 256 + tid] = __bfloat162float(p1h[pbase + j * 256 + tid]);
        __syncthreads();
        #pragma unroll 4
        for (int i = 0; i < 256; i++) {
            const float4 dv = *(const float4*)&Dp[((k * 256 + i) << 8) + q0];
            #pragma unroll
            for (int j = 0; j < 4; j++) {
                float a = tile[(nr0 + j) * 256 + i];
                acc[j][0] += a * dv.x;
                acc[j][1] += a * dv.y;
                acc[j][2] += a * dv.z;
                acc[j][3] += a * dv.w;
            }
        }
    }
    __syncthreads();
    float4 bc = *(const float4*)&comb_b1[q0];
    #pragma unroll
    for (int k = 0; k < K_; k++) {
        const float4 pp = *(const float4*)&ws[OFF_BC + k * 256 + q0];
        bc.x += pp.x; bc.y += pp.y; bc.z += pp.z; bc.w += pp.w;
    }
    for (int j = 0; j < 4; j++) {
        float4 pv;
        pv.x = gelu_f(acc[j][0] + bc.x);
        pv.y = gelu_f(acc[j][1] + bc.y);
        pv.z = gelu_f(acc[j][2] + bc.z);
        pv.w = gelu_f(acc[j][3] + bc.w);
        *(float4*)&tile[(nr0 + j) * 256 + q0] = pv;
    }
    __syncthreads();
    float hf[4][4];
    #pragma unroll
    for (int j = 0; j < 4; j++)
        for (int qq = 0; qq < 4; qq++) hf[j][qq] = 0.f;
    #pragma unroll 4
    for (int i = 0; i < 256; i++) {
        const float4 w2 = *(const float4*)&comb_w2[(i << 8) + q0];
        #pragma unroll
        for (int j = 0; j < 4; j++) {
            float a = tile[(nr0 + j) * 256 + i];
            hf[j][0] += a * w2.x;
            hf[j][1] += a * w2.y;
            hf[j][2] += a * w2.z;
            hf[j][3] += a * w2.w;
        }
    }
    const float4 cb2 = *(const float4*)&comb_b2[q0];
    const float4 zc = *(const float4*)&ws[OFF_ZWC + b * D_ + q0];
    for (int j = 0; j < 4; j++) {
        float4 zz;
        zz.x = zc.x + 0.3f * (hf[j][0] + cb2.x);
        zz.y = zc.y + 0.3f * (hf[j][1] + cb2.y);
        zz.z = zc.z + 0.3f * (hf[j][2] + cb2.z);
        zz.w = zc.w + 0.3f * (hf[j][3] + cb2.w);
        #pragma unroll
        for (int c = 0; c < C_; c++) {
            float xv = xwl[(nr0 + j) * C_ + c];
            const float4 wv = *(const float4*)&in_proj_w[(c << 8) + q0];
            zz.x += xv * wv.x;
            zz.y += xv * wv.y;
            zz.z += xv * wv.z;
            zz.w += xv * wv.w;
        }
        *(float4*)&out[((long)(b * N_ + n0 + nr0 + j) << 8) + q0] = zz;
    }
}

extern "C" void kernel_launch(void* const* d_in, const int* in_sizes, int n_in,
                              void* d_out, int out_size, void* d_ws, size_t ws_size,
                              hipStream_t stream) {
    const float* x = (const float*)d_in[0];
    const float* in_proj_w = (const float*)d_in[1];
    const float* in_proj_b = (const float*)d_in[2];
    const float* pe_w1 = (const float*)d_in[3];
    const float* pe_b1 = (const float*)d_in[4];
    const float* pe_w2 = (const float*)d_in[5];
    const float* pe_b2 = (const float*)d_in[6];
    const float* noise_w = (const float*)d_in[7];
    const float* noise_b = (const float*)d_in[8];
    const float* sfe_w1 = (const float*)d_in[9];
    const float* sfe_b1 = (const float*)d_in[10];
    const float* sfe_w2 = (const float*)d_in[11];
    const float* sfe_b2 = (const float*)d_in[12];
    const float* comb_w1 = (const float*)d_in[13];
    const float* comb_b1 = (const float*)d_in[14];
    const float* comb_w2 = (const float*)d_in[15];
    const float* comb_b2 = (const float*)d_in[16];
    const float* pool_param = (const float*)d_in[17];
    float* ws = (float*)d_ws;
    __hip_bfloat16* p1h = (__hip_bfloat16*)(ws + OFF_P1H);
    float* out = (float*)d_out;

    hipLaunchKernelGGL(k_spatial_mean, dim3(192), dim3(256), 0, stream, x, ws);
    hipLaunchKernelGGL(k_lag_dist, dim3(24, 4, 8), dim3(256), 0, stream, x, ws);
    hipLaunchKernelGGL(k_gating, dim3(8), dim3(128), 0, stream, pool_param, ws);
    hipLaunchKernelGGL(k_time_emb, dim3(192), dim3(128), 0, stream,
                       pe_w1, pe_b1, pe_w2, pe_b2, noise_w, noise_b, in_proj_b, ws);
    hipLaunchKernelGGL(k_te_reduce, dim3(8), dim3(256), 0, stream, in_proj_b, ws, out);
    hipLaunchKernelGGL(k_prep_ab, dim3(13), dim3(256), 0, stream, in_proj_w, sfe_w1, ws);
    hipLaunchKernelGGL(k_prep_d, dim3(16, 13), dim3(256), 0, stream, sfe_w2, comb_w1, ws);
    hipLaunchKernelGGL(k_prep_bias, dim3(13), dim3(256), 0, stream, sfe_b2, comb_w1, ws);
    hipLaunchKernelGGL(k_prep_c1, dim3(13, 8), dim3(256), 0, stream, sfe_w1, sfe_b1, ws);
    hipLaunchKernelGGL(k_xhat, dim3(64, 8), dim3(256), 0, stream, x, ws);
    hipLaunchKernelGGL(k_p1, dim3(16, 13, 8), dim3(256), 0, stream, ws, p1h);
    hipLaunchKernelGGL(k_final, dim3(64, 8), dim3(256), 0, stream,
                       ws, p1h, comb_w2, comb_b2, comb_b1, in_proj_w, out);
}

// Round 3
// 490.411 us; speedup vs baseline: 2.2106x; 1.4928x over previous
//
#include <hip/hip_runtime.h>
#include <hip/hip_bf16.h>
#include <math.h>

#define B_ 8
#define P_ 24
#define N_ 1024
#define C_ 16
#define D_ 256
#define K_ 13

// workspace offsets (in floats)
#define OFF_SM   0          // spatial_mean: 192*16
#define OFF_DL   4096       // d_lag: 8*4*24
#define OFF_ATT  8192       // att: 8*24
#define OFF_TE   12288      // te_fold: 192*256 (time_emb + in_proj_b)
#define OFF_FTR  65536      // Fte_re: 8*13*256
#define OFF_FTI  94208      // Fte_im
#define OFF_ZWC  122880     // zw_const: 8*256
#define OFF_AB   126976     // fused A/B: 13*32*256
#define OFF_C1   237568     // c1: 8*13*256
#define OFF_BC   266240     // bias_comb partials: 13*256
#define OFF_DD   270336     // Dt bf16 [k][q][i]: 13*256*256 ushorts = 425984 floats
#define OFF_W2E  696320     // W2ext bf16 [q2][288]: 36864 floats
#define OFF_XC   1126400    // Xhat re+im: 8*13*1024*32
#define OFF_XW   4538368    // xw: 8*1024*16
#define OFF_P1H  4673536    // p1 (bf16): 8*13*1024*256 ushorts

typedef unsigned short ushort_t;
typedef __bf16 bf16x8 __attribute__((ext_vector_type(8)));
typedef float f32x4 __attribute__((ext_vector_type(4)));
typedef unsigned short ushort8 __attribute__((ext_vector_type(8)));

__device__ __forceinline__ float gelu_f(float v) {
    return 0.5f * v * (1.0f + erff(v * 0.70710678118654752440f));
}
__device__ __forceinline__ float softplus_f(float z) {
    return fmaxf(z, 0.0f) + log1pf(expf(-fabsf(z)));
}
__device__ __forceinline__ ushort_t f2bf(float f) {
    union { float f; unsigned u; } v; v.f = f;
    unsigned r = v.u + 0x7fffu + ((v.u >> 16) & 1u);
    return (ushort_t)(r >> 16);
}

// ---- K1: spatial mean of x over N per (b,t) ----
__global__ void k_spatial_mean(const float* __restrict__ x, float* __restrict__ ws) {
    int bt = blockIdx.x;
    int tid = threadIdx.x;
    int c = tid & 15, ns = tid >> 4;
    const float* xp = x + (long)bt * (N_ * C_);
    float s = 0.f;
    for (int n = ns; n < N_; n += 16) s += xp[n * C_ + c];
    __shared__ float lds[256];
    lds[tid] = s;
    __syncthreads();
    for (int st = 128; st >= 16; st >>= 1) {
        if (tid < st) lds[tid] += lds[tid + st];
        __syncthreads();
    }
    if (tid < 16) ws[OFF_SM + bt * 16 + tid] = lds[tid] * (1.0f / 1024.0f);
}

// ---- K2: lag distances ----
__device__ __forceinline__ float xr_at(const float* xp, int t, int idx) {
    float xt = xp[(long)t * (N_ * C_) + idx];
    if (t == 0) return 0.f;
    if (t == 1) return xt - xp[idx];
    float a = xp[(long)(t - 1) * (N_ * C_) + idx];
    float b = xp[(long)(t - 2) * (N_ * C_) + idx];
    return xt - (xt + a + b) / 3.0f;
}
__global__ void k_lag_dist(const float* __restrict__ x, float* __restrict__ ws) {
    int t = blockIdx.x, li = blockIdx.y, b = blockIdx.z;
    const int lags[4] = {1, 2, 4, 6};
    int lag = lags[li];
    int tid = threadIdx.x;
    __shared__ float lds[256];
    float out = 0.f;
    if (t >= lag) {
        const float* xp = x + (long)b * P_ * N_ * C_;
        float s = 0.f;
        for (int idx = tid; idx < N_ * C_; idx += 256)
            s += fabsf(xr_at(xp, t, idx) - xr_at(xp, t - lag, idx));
        lds[tid] = s;
        __syncthreads();
        for (int st = 128; st > 0; st >>= 1) {
            if (tid < st) lds[tid] += lds[tid + st];
            __syncthreads();
        }
        out = lds[0] * (1.0f / (N_ * C_));
    }
    if (tid == 0) ws[OFF_DL + (b * 4 + li) * P_ + t] = out;
}

// ---- K3: gating -> att  (rank-select median, all-LDS) ----
__global__ void k_gating(const float* __restrict__ pool_param, float* __restrict__ ws) {
    int b = blockIdx.x;
    int tid = threadIdx.x;  // 128
    int li = tid / P_, t = tid - li * P_;
    bool active = tid < 4 * P_;
    __shared__ float d[4][P_], ad[4][P_], med[4], mad[4], g[P_], gbuf[P_];
    if (active) d[li][t] = ws[OFF_DL + (b * 4 + li) * P_ + t];
    __syncthreads();
    if (active) {
        float v = d[li][t];
        int rank = 0;
        #pragma unroll
        for (int j = 0; j < P_; j++) {
            float dj = d[li][j];
            rank += (dj < v || (dj == v && j < t)) ? 1 : 0;
        }
        if (rank == 11) med[li] = v;
    }
    __syncthreads();
    if (active) ad[li][t] = fabsf(d[li][t] - med[li]);
    __syncthreads();
    if (active) {
        float v = ad[li][t];
        int rank = 0;
        #pragma unroll
        for (int j = 0; j < P_; j++) {
            float dj = ad[li][j];
            rank += (dj < v || (dj == v && j < t)) ? 1 : 0;
        }
        if (rank == 11) mad[li] = v;
    }
    __syncthreads();
    if (active) {
        float z = (d[li][t] - med[li]) / (mad[li] * 1.4826f + 1e-6f);
        ad[li][t] = softplus_f(z);
    }
    __syncthreads();
    if (tid < P_) g[tid] = 0.25f * (ad[0][tid] + ad[1][tid] + ad[2][tid] + ad[3][tid]);
    __syncthreads();
    if (tid == 0) {
        float c = g[0];
        gbuf[0] = g[0];
        for (int tt = 1; tt < P_; tt++) { c = 0.6f * c + 0.4f * g[tt]; gbuf[tt] = c; }
        float mean = 0.f;
        for (int tt = 0; tt < P_; tt++) mean += gbuf[tt];
        mean *= (1.0f / P_);
        float gate[P_];
        #pragma unroll
        for (int tt = 0; tt < P_; tt++) gate[tt] = 1.0f / (1.0f + expf(-1.5f * (gbuf[tt] - mean)));
        float m = -1e30f;
        float pp[P_];
        #pragma unroll
        for (int tt = 0; tt < P_; tt++) { pp[tt] = pool_param[tt]; m = fmaxf(m, pp[tt]); }
        float ssum = 0.f;
        #pragma unroll
        for (int tt = 0; tt < P_; tt++) { pp[tt] = expf(pp[tt] - m); ssum += pp[tt]; }
        float m2 = -1e30f;
        #pragma unroll
        for (int tt = 0; tt < P_; tt++) { pp[tt] = (pp[tt] / ssum) * (1.0f + gate[tt]); m2 = fmaxf(m2, pp[tt]); }
        float s2 = 0.f;
        #pragma unroll
        for (int tt = 0; tt < P_; tt++) { pp[tt] = expf(pp[tt] - m2); s2 += pp[tt]; }
        #pragma unroll
        for (int tt = 0; tt < P_; tt++) ws[OFF_ATT + b * P_ + tt] = pp[tt] / s2;
    }
}

// ---- K4: time_emb (+ in_proj_b folded) ----
__global__ void k_time_emb(const float* __restrict__ pe_w1, const float* __restrict__ pe_b1,
                           const float* __restrict__ pe_w2, const float* __restrict__ pe_b2,
                           const float* __restrict__ noise_w, const float* __restrict__ noise_b,
                           const float* __restrict__ in_proj_b, float* __restrict__ ws) {
    int bt = blockIdx.x;
    int t = bt % P_;
    int tid = threadIdx.x;  // 128
    int k = tid >> 6, o = tid & 63;
    __shared__ float p1e[128];
    float period = (k == 0) ? 24.0f : 72.0f;
    float ph = 6.283185307179586f * (float)t / period;
    float sv = sinf(ph), cv = cosf(ph);
    float v = sv * pe_w1[(k * 2 + 0) * 64 + o] + cv * pe_w1[(k * 2 + 1) * 64 + o] + pe_b1[k * 64 + o];
    p1e[tid] = gelu_f(v);
    __syncthreads();
    float acc = pe_b2[k * 64 + o];
    for (int i = 0; i < 64; i++) acc += p1e[k * 64 + i] * pe_w2[(k * 64 + i) * 64 + o];
    ws[OFF_TE + bt * D_ + tid] = acc + in_proj_b[tid];
    float nacc = noise_b[tid];
    for (int c = 0; c < C_; c++) nacc += ws[OFF_SM + bt * C_ + c] * noise_w[c * 128 + tid];
    ws[OFF_TE + bt * D_ + 128 + tid] = nacc + in_proj_b[128 + tid];
}

// ---- K5: DFT of te_fold, att-weighted te, time_vec ----
__global__ void k_te_reduce(const float* __restrict__ in_proj_b, float* __restrict__ ws,
                            float* __restrict__ out) {
    int b = blockIdx.x;
    int tid = threadIdx.x;  // 256 = channel
    __shared__ float ct[K_ * P_], st[K_ * P_], attl[P_];
    for (int i = tid; i < K_ * P_; i += 256) {
        int k = i / P_, t = i % P_;
        int r = (k * t) % P_;
        float ph = 6.283185307179586f * (float)r / (float)P_;
        ct[i] = cosf(ph);
        st[i] = sinf(ph);
    }
    if (tid < P_) attl[tid] = ws[OFF_ATT + b * P_ + tid];
    __syncthreads();
    float fre[K_], fim[K_];
    #pragma unroll
    for (int k = 0; k < K_; k++) { fre[k] = 0.f; fim[k] = 0.f; }
    float sm = 0.f, sa = 0.f;
    for (int t = 0; t < P_; t++) {
        float v = ws[OFF_TE + (b * P_ + t) * D_ + tid];
        sm += v;
        sa += attl[t] * v;
        #pragma unroll
        for (int k = 0; k < K_; k++) {
            fre[k] += ct[k * P_ + t] * v;
            fim[k] -= st[k * P_ + t] * v;
        }
    }
    out[2097152 + b * D_ + tid] = sm * (1.0f / P_) - in_proj_b[tid];
    ws[OFF_ZWC + b * D_ + tid] = sa;
    #pragma unroll
    for (int k = 0; k < K_; k++) {
        ws[OFF_FTR + (b * K_ + k) * D_ + tid] = fre[k];
        ws[OFF_FTI + (b * K_ + k) * D_ + tid] = fim[k];
    }
}

// ---- K6a: A_k = W_in @ W1re_k, B_k = W_in @ W1im_k ----
__global__ void k_prep_ab(const float* __restrict__ in_proj_w, const float* __restrict__ sfe_w1,
                          float* __restrict__ ws) {
    int k = blockIdx.x;
    int o = threadIdx.x;
    float accA[C_], accB[C_];
    #pragma unroll
    for (int c = 0; c < C_; c++) { accA[c] = 0.f; accB[c] = 0.f; }
    const float* w1r = sfe_w1 + (long)k * 512 * 256;
    const float* w1i = w1r + 256 * 256;
    for (int e = 0; e < 256; e++) {
        float vr = w1r[e * 256 + o];
        float vi = w1i[e * 256 + o];
        #pragma unroll
        for (int c = 0; c < C_; c++) {
            float w = in_proj_w[c * 256 + e];
            accA[c] += w * vr;
            accB[c] += w * vi;
        }
    }
    for (int c = 0; c < C_; c++) {
        ws[OFF_AB + (k * 32 + c) * 256 + o] = accA[c];
        ws[OFF_AB + (k * 32 + 16 + c) * 256 + o] = accB[c];
    }
}

// ---- K6b: Dt[k][q][i] = (sfe_w2[k] @ comb_w1[k-block])^T, bf16 ----
__global__ void k_prep_d(const float* __restrict__ sfe_w2, const float* __restrict__ comb_w1,
                         float* __restrict__ ws) {
    int itile = blockIdx.x, k = blockIdx.y;
    int q = threadIdx.x;
    float acc[16];
    #pragma unroll
    for (int i = 0; i < 16; i++) acc[i] = 0.f;
    for (int o = 0; o < 256; o++) {
        float cw = comb_w1[((k * 256 + o) << 8) + q];
        #pragma unroll
        for (int i2 = 0; i2 < 16; i2++)
            acc[i2] += sfe_w2[(k * 256 + itile * 16 + i2) * 256 + o] * cw;
    }
    ushort_t* dtp = (ushort_t*)(ws + OFF_DD);
    for (int i2 = 0; i2 < 16; i2++)
        dtp[((k * 256 + q) << 8) + itile * 16 + i2] = f2bf(acc[i2]);
}

// ---- K6c: c1[b,k,:] = Fte_re@W1re + Fte_im@W1im + sfe_b1 ----
__global__ void k_prep_c1(const float* __restrict__ sfe_w1, const float* __restrict__ sfe_b1,
                          float* __restrict__ ws) {
    int k = blockIdx.x, b = blockIdx.y;
    int o = threadIdx.x;
    float acc = sfe_b1[k * 256 + o];
    const float* w1 = sfe_w1 + (long)k * 512 * 256;
    const float* fr = ws + OFF_FTR + (b * K_ + k) * D_;
    const float* fi = ws + OFF_FTI + (b * K_ + k) * D_;
    for (int c = 0; c < 256; c++)
        acc += fr[c] * w1[c * 256 + o] + fi[c] * w1[(256 + c) * 256 + o];
    ws[OFF_C1 + (b * K_ + k) * D_ + o] = acc;
}

// ---- K6d: bias_comb partial per k ----
__global__ void k_prep_bias(const float* __restrict__ sfe_b2, const float* __restrict__ comb_w1,
                            float* __restrict__ ws) {
    int k = blockIdx.x;
    int q = threadIdx.x;
    float acc = 0.f;
    for (int o = 0; o < 256; o++)
        acc += sfe_b2[k * 256 + o] * comb_w1[((k * 256 + o) << 8) + q];
    ws[OFF_BC + k * 256 + q] = acc;
}

// ---- K6e: W2ext bf16 [q2][288] = [comb_w2^T | in_proj_w^T/0.3 | 0] ----
__global__ void k_prep_w2(const float* __restrict__ comb_w2, const float* __restrict__ in_proj_w,
                          float* __restrict__ ws) {
    int q2 = blockIdx.x;
    ushort_t* w2e = (ushort_t*)(ws + OFF_W2E);
    for (int i = threadIdx.x; i < 288; i += 128) {
        float v = 0.f;
        if (i < 256) v = comb_w2[(i << 8) + q2];
        else if (i < 272) v = in_proj_w[((i - 256) << 8) + q2] * (1.0f / 0.3f);
        w2e[q2 * 288 + i] = f2bf(v);
    }
}

// ---- K7: Xhat (DFT of x over t) + att-weighted x ----
__global__ void k_xhat(const float* __restrict__ x, float* __restrict__ ws) {
    int ntile = blockIdx.x, b = blockIdx.y;
    int tid = threadIdx.x;
    int n = ntile * 16 + (tid >> 4), c = tid & 15;
    __shared__ float ct[K_ * P_], st[K_ * P_], attl[P_];
    for (int i = tid; i < K_ * P_; i += 256) {
        int k = i / P_, t = i % P_;
        int r = (k * t) % P_;
        float ph = 6.283185307179586f * (float)r / (float)P_;
        ct[i] = cosf(ph);
        st[i] = sinf(ph);
    }
    if (tid < P_) attl[tid] = ws[OFF_ATT + b * P_ + tid];
    __syncthreads();
    float re[K_], im[K_], xwa = 0.f;
    #pragma unroll
    for (int k = 0; k < K_; k++) { re[k] = 0.f; im[k] = 0.f; }
    for (int t = 0; t < P_; t++) {
        float v = x[((long)(b * P_ + t) * N_ + n) * C_ + c];
        xwa += attl[t] * v;
        #pragma unroll
        for (int k = 0; k < K_; k++) {
            re[k] += ct[k * P_ + t] * v;
            im[k] -= st[k * P_ + t] * v;
        }
    }
    #pragma unroll
    for (int k = 0; k < K_; k++) {
        long xb = OFF_XC + ((long)(b * K_ + k) * N_ + n) * 32;
        ws[xb + c] = re[k];
        ws[xb + 16 + c] = im[k];
    }
    ws[OFF_XW + ((long)b * N_ + n) * C_ + c] = xwa;
}

// ---- K8: p1 = gelu(Xc @ AB_k + c1), stored bf16 ----
__global__ void k_p1(const float* __restrict__ ws, __hip_bfloat16* __restrict__ p1h) {
    int ntile = blockIdx.x, k = blockIdx.y, b = blockIdx.z;
    int o = threadIdx.x;
    __shared__ float xs[64 * 32];
    long xbase = OFF_XC + ((long)(b * K_ + k) * N_ + ntile * 64) * 32;
    for (int j = 0; j < 8; j++) xs[j * 256 + o] = ws[xbase + j * 256 + o];
    float ab[32];
    #pragma unroll
    for (int e = 0; e < 32; e++) ab[e] = ws[OFF_AB + (k * 32 + e) * 256 + o];
    float c1v = ws[OFF_C1 + (b * K_ + k) * D_ + o];
    __syncthreads();
    long pbase = ((long)(b * K_ + k) * N_ + ntile * 64) * 256;
    for (int np = 0; np < 64; np++) {
        const float4* xrow = (const float4*)&xs[np * 32];
        float acc = c1v;
        #pragma unroll
        for (int e4 = 0; e4 < 8; e4++) {
            float4 p = xrow[e4];
            acc += p.x * ab[e4 * 4] + p.y * ab[e4 * 4 + 1] + p.z * ab[e4 * 4 + 2] + p.w * ab[e4 * 4 + 3];
        }
        acc = gelu_f(acc);
        p1h[pbase + np * 256 + o] = __float2bfloat16(acc);
    }
}

// ---- K9: MFMA GEMM1 (sum_k p1@D_k) -> gelu -> MFMA GEMM2 (@W2ext) -> z ----
// block: 512 thr = 8 waves; tile 32n x 256q; grid (32 ntiles, 8 b)
// A-frag: lane holds A[m=lane&15][k=quad*8+j]; B-frag: B[k=quad*8+j][n=lane&15]
// C/D: col=lane&15, row=quad*4+reg  [verified m89/m91]
__global__ __launch_bounds__(512) void k_final(
        const float* __restrict__ ws, const ushort_t* __restrict__ p1h,
        const float* __restrict__ comb_b1, const float* __restrict__ comb_b2,
        float* __restrict__ out) {
    int ntile = blockIdx.x, b = blockIdx.y;
    int n0 = ntile * 32;
    int tid = threadIdx.x;
    int lane = tid & 63, wave = tid >> 6;
    int l15 = lane & 15, quad = lane >> 4;
    int wq0 = wave * 32;
    __shared__ ushort_t sh[32 * 296];  // GEMM1 A-slab (stride 264) then Uext (stride 296)
    const ushort_t* dt = (const ushort_t*)(ws + OFF_DD);
    const ushort_t* w2e = (const ushort_t*)(ws + OFF_W2E);

    f32x4 acc00 = {}, acc01 = {}, acc10 = {}, acc11 = {};
    for (int k = 0; k < K_; k++) {
        __syncthreads();
        long pbase = ((long)((b * K_ + k) * N_) + n0) * 256;
        #pragma unroll
        for (int p = 0; p < 2; p++) {
            int cidx = p * 512 + tid;       // 1024 chunks of 8 bf16
            int row = cidx >> 5, col8 = (cidx & 31) << 3;
            *(ushort8*)&sh[row * 264 + col8] = *(const ushort8*)&p1h[pbase + row * 256 + col8];
        }
        __syncthreads();
        #pragma unroll
        for (int s = 0; s < 8; s++) {
            int i0 = s * 32;
            bf16x8 a0 = *(const bf16x8*)&sh[l15 * 264 + i0 + quad * 8];
            bf16x8 a1 = *(const bf16x8*)&sh[(16 + l15) * 264 + i0 + quad * 8];
            const ushort_t* db = dt + (((k * 256 + wq0 + l15) << 8) + i0 + quad * 8);
            bf16x8 b0 = *(const bf16x8*)db;
            bf16x8 b1 = *(const bf16x8*)(db + (16 << 8));
            acc00 = __builtin_amdgcn_mfma_f32_16x16x32_bf16(a0, b0, acc00, 0, 0, 0);
            acc01 = __builtin_amdgcn_mfma_f32_16x16x32_bf16(a0, b1, acc01, 0, 0, 0);
            acc10 = __builtin_amdgcn_mfma_f32_16x16x32_bf16(a1, b0, acc10, 0, 0, 0);
            acc11 = __builtin_amdgcn_mfma_f32_16x16x32_bf16(a1, b1, acc11, 0, 0, 0);
        }
    }
    __syncthreads();
    // bias (comb_b1 + 13 partials) + gelu -> Uext bf16
    int q0 = wq0 + l15, q1 = wq0 + 16 + l15;
    float bc0 = comb_b1[q0], bc1 = comb_b1[q1];
    #pragma unroll
    for (int k = 0; k < K_; k++) {
        bc0 += ws[OFF_BC + k * 256 + q0];
        bc1 += ws[OFF_BC + k * 256 + q1];
    }
    #pragma unroll
    for (int r = 0; r < 4; r++) {
        int na = quad * 4 + r, nb = 16 + quad * 4 + r;
        sh[na * 296 + q0] = f2bf(gelu_f(acc00[r] + bc0));
        sh[na * 296 + q1] = f2bf(gelu_f(acc01[r] + bc1));
        sh[nb * 296 + q0] = f2bf(gelu_f(acc10[r] + bc0));
        sh[nb * 296 + q1] = f2bf(gelu_f(acc11[r] + bc1));
    }
    // xw columns (256..271) + zero pad (272..287)
    {
        int row = tid >> 4, cc = tid & 15;
        float xv = ws[OFF_XW + ((long)b * N_ + n0 + row) * C_ + cc];
        sh[row * 296 + 256 + cc] = f2bf(xv);
        sh[row * 296 + 272 + cc] = 0;
    }
    __syncthreads();
    f32x4 h00 = {}, h01 = {}, h10 = {}, h11 = {};
    #pragma unroll
    for (int s = 0; s < 9; s++) {
        int i0 = s * 32;
        bf16x8 a0 = *(const bf16x8*)&sh[l15 * 296 + i0 + quad * 8];
        bf16x8 a1 = *(const bf16x8*)&sh[(16 + l15) * 296 + i0 + quad * 8];
        const ushort_t* wb = w2e + ((wq0 + l15) * 288 + i0 + quad * 8);
        bf16x8 b0 = *(const bf16x8*)wb;
        bf16x8 b1 = *(const bf16x8*)(wb + 16 * 288);
        h00 = __builtin_amdgcn_mfma_f32_16x16x32_bf16(a0, b0, h00, 0, 0, 0);
        h01 = __builtin_amdgcn_mfma_f32_16x16x32_bf16(a0, b1, h01, 0, 0, 0);
        h10 = __builtin_amdgcn_mfma_f32_16x16x32_bf16(a1, b0, h10, 0, 0, 0);
        h11 = __builtin_amdgcn_mfma_f32_16x16x32_bf16(a1, b1, h11, 0, 0, 0);
    }
    // epilogue: z = zc + 0.3*(hf + cb2)  (xw@Win rides in hf pre-scaled by 1/0.3)
    float zc0 = ws[OFF_ZWC + b * 256 + q0], zc1 = ws[OFF_ZWC + b * 256 + q1];
    float cb0 = comb_b2[q0], cb1 = comb_b2[q1];
    long ob = ((long)b * N_ + n0) << 8;
    #pragma unroll
    for (int r = 0; r < 4; r++) {
        int na = quad * 4 + r, nb = 16 + quad * 4 + r;
        out[ob + ((long)na << 8) + q0] = zc0 + 0.3f * (h00[r] + cb0);
        out[ob + ((long)na << 8) + q1] = zc1 + 0.3f * (h01[r] + cb1);
        out[ob + ((long)nb << 8) + q0] = zc0 + 0.3f * (h10[r] + cb0);
        out[ob + ((long)nb << 8) + q1] = zc1 + 0.3f * (h11[r] + cb1);
    }
}

extern "C" void kernel_launch(void* const* d_in, const int* in_sizes, int n_in,
                              void* d_out, int out_size, void* d_ws, size_t ws_size,
                              hipStream_t stream) {
    const float* x = (const float*)d_in[0];
    const float* in_proj_w = (const float*)d_in[1];
    const float* in_proj_b = (const float*)d_in[2];
    const float* pe_w1 = (const float*)d_in[3];
    const float* pe_b1 = (const float*)d_in[4];
    const float* pe_w2 = (const float*)d_in[5];
    const float* pe_b2 = (const float*)d_in[6];
    const float* noise_w = (const float*)d_in[7];
    const float* noise_b = (const float*)d_in[8];
    const float* sfe_w1 = (const float*)d_in[9];
    const float* sfe_b1 = (const float*)d_in[10];
    const float* sfe_w2 = (const float*)d_in[11];
    const float* sfe_b2 = (const float*)d_in[12];
    const float* comb_w1 = (const float*)d_in[13];
    const float* comb_b1 = (const float*)d_in[14];
    const float* comb_w2 = (const float*)d_in[15];
    const float* comb_b2 = (const float*)d_in[16];
    const float* pool_param = (const float*)d_in[17];
    float* ws = (float*)d_ws;
    __hip_bfloat16* p1h = (__hip_bfloat16*)(ws + OFF_P1H);
    float* out = (float*)d_out;

    hipLaunchKernelGGL(k_spatial_mean, dim3(192), dim3(256), 0, stream, x, ws);
    hipLaunchKernelGGL(k_lag_dist, dim3(24, 4, 8), dim3(256), 0, stream, x, ws);
    hipLaunchKernelGGL(k_gating, dim3(8), dim3(128), 0, stream, pool_param, ws);
    hipLaunchKernelGGL(k_time_emb, dim3(192), dim3(128), 0, stream,
                       pe_w1, pe_b1, pe_w2, pe_b2, noise_w, noise_b, in_proj_b, ws);
    hipLaunchKernelGGL(k_te_reduce, dim3(8), dim3(256), 0, stream, in_proj_b, ws, out);
    hipLaunchKernelGGL(k_prep_ab, dim3(13), dim3(256), 0, stream, in_proj_w, sfe_w1, ws);
    hipLaunchKernelGGL(k_prep_d, dim3(16, 13), dim3(256), 0, stream, sfe_w2, comb_w1, ws);
    hipLaunchKernelGGL(k_prep_bias, dim3(13), dim3(256), 0, stream, sfe_b2, comb_w1, ws);
    hipLaunchKernelGGL(k_prep_w2, dim3(256), dim3(128), 0, stream, comb_w2, in_proj_w, ws);
    hipLaunchKernelGGL(k_prep_c1, dim3(13, 8), dim3(256), 0, stream, sfe_w1, sfe_b1, ws);
    hipLaunchKernelGGL(k_xhat, dim3(64, 8), dim3(256), 0, stream, x, ws);
    hipLaunchKernelGGL(k_p1, dim3(16, 13, 8), dim3(256), 0, stream, ws, p1h);
    hipLaunchKernelGGL(k_final, dim3(32, 8), dim3(512), 0, stream,
                       ws, (const ushort_t*)p1h, comb_b1, comb_b2, out);
}

// Round 4
// 389.262 us; speedup vs baseline: 2.7851x; 1.2598x over previous
//
#include <hip/hip_runtime.h>
#include <hip/hip_bf16.h>
#include <math.h>

#define B_ 8
#define P_ 24
#define N_ 1024
#define C_ 16
#define D_ 256
#define K_ 13

// workspace offsets (in floats)
#define OFF_SM   0          // spatial_mean: 192*16
#define OFF_DL   4096       // d_lag: 8*4*24
#define OFF_ATT  8192       // att: 8*24
#define OFF_TE   12288      // te_fold: 192*256 (time_emb + in_proj_b)
#define OFF_FTR  65536      // Fte_re: 8*13*256
#define OFF_FTI  94208      // Fte_im
#define OFF_ZWC  122880     // zw_const: 8*256
#define OFF_AB   126976     // ABt bf16 [k][o][32]: 13*256*32 ushorts
#define OFF_C1   237568     // c1: 8*13*256
#define OFF_BC   266240     // bias_comb partials: 13*256
#define OFF_DD   270336     // Dt bf16 [k][q][i]: 13*256*256 ushorts
#define OFF_W2E  696320     // W2ext bf16 [q2][288]
#define OFF_XC   1126400    // Xhat bf16 [b][k][n][32]: 8*13*1024*32 ushorts
#define OFF_XW   2830336    // xw fp32: 8*1024*16

typedef unsigned short ushort_t;
typedef __bf16 bf16x8 __attribute__((ext_vector_type(8)));
typedef float f32x4 __attribute__((ext_vector_type(4)));
typedef unsigned short ushort8 __attribute__((ext_vector_type(8)));

__device__ __forceinline__ float gelu_f(float v) {
    return 0.5f * v * (1.0f + erff(v * 0.70710678118654752440f));
}
__device__ __forceinline__ float softplus_f(float z) {
    return fmaxf(z, 0.0f) + log1pf(expf(-fabsf(z)));
}
__device__ __forceinline__ ushort_t f2bf(float f) {
    union { float f; unsigned u; } v; v.f = f;
    unsigned r = v.u + 0x7fffu + ((v.u >> 16) & 1u);
    return (ushort_t)(r >> 16);
}

// ---- K1: spatial mean of x over N per (b,t) ----
__global__ void k_spatial_mean(const float* __restrict__ x, float* __restrict__ ws) {
    int bt = blockIdx.x;
    int tid = threadIdx.x;
    int c = tid & 15, ns = tid >> 4;
    const float* xp = x + (long)bt * (N_ * C_);
    float s = 0.f;
    for (int n = ns; n < N_; n += 16) s += xp[n * C_ + c];
    __shared__ float lds[256];
    lds[tid] = s;
    __syncthreads();
    for (int st = 128; st >= 16; st >>= 1) {
        if (tid < st) lds[tid] += lds[tid + st];
        __syncthreads();
    }
    if (tid < 16) ws[OFF_SM + bt * 16 + tid] = lds[tid] * (1.0f / 1024.0f);
}

// ---- K2: lag distances ----
__device__ __forceinline__ float xr_at(const float* xp, int t, int idx) {
    float xt = xp[(long)t * (N_ * C_) + idx];
    if (t == 0) return 0.f;
    if (t == 1) return xt - xp[idx];
    float a = xp[(long)(t - 1) * (N_ * C_) + idx];
    float b = xp[(long)(t - 2) * (N_ * C_) + idx];
    return xt - (xt + a + b) / 3.0f;
}
__global__ void k_lag_dist(const float* __restrict__ x, float* __restrict__ ws) {
    int t = blockIdx.x, li = blockIdx.y, b = blockIdx.z;
    const int lags[4] = {1, 2, 4, 6};
    int lag = lags[li];
    int tid = threadIdx.x;
    __shared__ float lds[256];
    float out = 0.f;
    if (t >= lag) {
        const float* xp = x + (long)b * P_ * N_ * C_;
        float s = 0.f;
        for (int idx = tid; idx < N_ * C_; idx += 256)
            s += fabsf(xr_at(xp, t, idx) - xr_at(xp, t - lag, idx));
        lds[tid] = s;
        __syncthreads();
        for (int st = 128; st > 0; st >>= 1) {
            if (tid < st) lds[tid] += lds[tid + st];
            __syncthreads();
        }
        out = lds[0] * (1.0f / (N_ * C_));
    }
    if (tid == 0) ws[OFF_DL + (b * 4 + li) * P_ + t] = out;
}

// ---- K3: gating -> att  (rank-select median, all-LDS) ----
__global__ void k_gating(const float* __restrict__ pool_param, float* __restrict__ ws) {
    int b = blockIdx.x;
    int tid = threadIdx.x;  // 128
    int li = tid / P_, t = tid - li * P_;
    bool active = tid < 4 * P_;
    __shared__ float d[4][P_], ad[4][P_], med[4], mad[4], g[P_], gbuf[P_];
    if (active) d[li][t] = ws[OFF_DL + (b * 4 + li) * P_ + t];
    __syncthreads();
    if (active) {
        float v = d[li][t];
        int rank = 0;
        #pragma unroll
        for (int j = 0; j < P_; j++) {
            float dj = d[li][j];
            rank += (dj < v || (dj == v && j < t)) ? 1 : 0;
        }
        if (rank == 11) med[li] = v;
    }
    __syncthreads();
    if (active) ad[li][t] = fabsf(d[li][t] - med[li]);
    __syncthreads();
    if (active) {
        float v = ad[li][t];
        int rank = 0;
        #pragma unroll
        for (int j = 0; j < P_; j++) {
            float dj = ad[li][j];
            rank += (dj < v || (dj == v && j < t)) ? 1 : 0;
        }
        if (rank == 11) mad[li] = v;
    }
    __syncthreads();
    if (active) {
        float z = (d[li][t] - med[li]) / (mad[li] * 1.4826f + 1e-6f);
        ad[li][t] = softplus_f(z);
    }
    __syncthreads();
    if (tid < P_) g[tid] = 0.25f * (ad[0][tid] + ad[1][tid] + ad[2][tid] + ad[3][tid]);
    __syncthreads();
    if (tid == 0) {
        float c = g[0];
        gbuf[0] = g[0];
        for (int tt = 1; tt < P_; tt++) { c = 0.6f * c + 0.4f * g[tt]; gbuf[tt] = c; }
        float mean = 0.f;
        for (int tt = 0; tt < P_; tt++) mean += gbuf[tt];
        mean *= (1.0f / P_);
        float gate[P_];
        #pragma unroll
        for (int tt = 0; tt < P_; tt++) gate[tt] = 1.0f / (1.0f + expf(-1.5f * (gbuf[tt] - mean)));
        float m = -1e30f;
        float pp[P_];
        #pragma unroll
        for (int tt = 0; tt < P_; tt++) { pp[tt] = pool_param[tt]; m = fmaxf(m, pp[tt]); }
        float ssum = 0.f;
        #pragma unroll
        for (int tt = 0; tt < P_; tt++) { pp[tt] = expf(pp[tt] - m); ssum += pp[tt]; }
        float m2 = -1e30f;
        #pragma unroll
        for (int tt = 0; tt < P_; tt++) { pp[tt] = (pp[tt] / ssum) * (1.0f + gate[tt]); m2 = fmaxf(m2, pp[tt]); }
        float s2 = 0.f;
        #pragma unroll
        for (int tt = 0; tt < P_; tt++) { pp[tt] = expf(pp[tt] - m2); s2 += pp[tt]; }
        #pragma unroll
        for (int tt = 0; tt < P_; tt++) ws[OFF_ATT + b * P_ + tt] = pp[tt] / s2;
    }
}

// ---- K4: time_emb (+ in_proj_b folded) ----
__global__ void k_time_emb(const float* __restrict__ pe_w1, const float* __restrict__ pe_b1,
                           const float* __restrict__ pe_w2, const float* __restrict__ pe_b2,
                           const float* __restrict__ noise_w, const float* __restrict__ noise_b,
                           const float* __restrict__ in_proj_b, float* __restrict__ ws) {
    int bt = blockIdx.x;
    int t = bt % P_;
    int tid = threadIdx.x;  // 128
    int k = tid >> 6, o = tid & 63;
    __shared__ float p1e[128];
    float period = (k == 0) ? 24.0f : 72.0f;
    float ph = 6.283185307179586f * (float)t / period;
    float sv = sinf(ph), cv = cosf(ph);
    float v = sv * pe_w1[(k * 2 + 0) * 64 + o] + cv * pe_w1[(k * 2 + 1) * 64 + o] + pe_b1[k * 64 + o];
    p1e[tid] = gelu_f(v);
    __syncthreads();
    float acc = pe_b2[k * 64 + o];
    for (int i = 0; i < 64; i++) acc += p1e[k * 64 + i] * pe_w2[(k * 64 + i) * 64 + o];
    ws[OFF_TE + bt * D_ + tid] = acc + in_proj_b[tid];
    float nacc = noise_b[tid];
    for (int c = 0; c < C_; c++) nacc += ws[OFF_SM + bt * C_ + c] * noise_w[c * 128 + tid];
    ws[OFF_TE + bt * D_ + 128 + tid] = nacc + in_proj_b[128 + tid];
}

// ---- K5: DFT of te_fold, att-weighted te, time_vec ----
__global__ void k_te_reduce(const float* __restrict__ in_proj_b, float* __restrict__ ws,
                            float* __restrict__ out) {
    int b = blockIdx.x;
    int tid = threadIdx.x;  // 256 = channel
    __shared__ float ct[K_ * P_], st[K_ * P_], attl[P_];
    for (int i = tid; i < K_ * P_; i += 256) {
        int k = i / P_, t = i % P_;
        int r = (k * t) % P_;
        float ph = 6.283185307179586f * (float)r / (float)P_;
        ct[i] = cosf(ph);
        st[i] = sinf(ph);
    }
    if (tid < P_) attl[tid] = ws[OFF_ATT + b * P_ + tid];
    __syncthreads();
    float fre[K_], fim[K_];
    #pragma unroll
    for (int k = 0; k < K_; k++) { fre[k] = 0.f; fim[k] = 0.f; }
    float sm = 0.f, sa = 0.f;
    for (int t = 0; t < P_; t++) {
        float v = ws[OFF_TE + (b * P_ + t) * D_ + tid];
        sm += v;
        sa += attl[t] * v;
        #pragma unroll
        for (int k = 0; k < K_; k++) {
            fre[k] += ct[k * P_ + t] * v;
            fim[k] -= st[k * P_ + t] * v;
        }
    }
    out[2097152 + b * D_ + tid] = sm * (1.0f / P_) - in_proj_b[tid];
    ws[OFF_ZWC + b * D_ + tid] = sa;
    #pragma unroll
    for (int k = 0; k < K_; k++) {
        ws[OFF_FTR + (b * K_ + k) * D_ + tid] = fre[k];
        ws[OFF_FTI + (b * K_ + k) * D_ + tid] = fim[k];
    }
}

// ---- K6a: ABt[k][o][e] bf16, e in [0,32): re=W_in@W1re, im=W_in@W1im ----
__global__ void k_prep_ab(const float* __restrict__ in_proj_w, const float* __restrict__ sfe_w1,
                          float* __restrict__ ws) {
    int k = blockIdx.x;
    int o = threadIdx.x;
    float accA[C_], accB[C_];
    #pragma unroll
    for (int c = 0; c < C_; c++) { accA[c] = 0.f; accB[c] = 0.f; }
    const float* w1r = sfe_w1 + (long)k * 512 * 256;
    const float* w1i = w1r + 256 * 256;
    for (int e = 0; e < 256; e++) {
        float vr = w1r[e * 256 + o];
        float vi = w1i[e * 256 + o];
        #pragma unroll
        for (int c = 0; c < C_; c++) {
            float w = in_proj_w[c * 256 + e];   // wave-uniform -> scalar load
            accA[c] += w * vr;
            accB[c] += w * vi;
        }
    }
    ushort_t* abt = (ushort_t*)(ws + OFF_AB);
    for (int c = 0; c < C_; c++) {
        abt[(k * 256 + o) * 32 + c] = f2bf(accA[c]);
        abt[(k * 256 + o) * 32 + 16 + c] = f2bf(accB[c]);
    }
}

// ---- K6b: Dt[k][q][i] = (sfe_w2[k] @ comb_w1[k-block])^T, bf16; LDS-tiled ----
__global__ void k_prep_d(const float* __restrict__ sfe_w2, const float* __restrict__ comb_w1,
                         float* __restrict__ ws) {
    int qt0 = blockIdx.x * 64, it0 = blockIdx.y * 64, k = blockIdx.z;
    int tid = threadIdx.x;
    int tq = tid & 15, ti = tid >> 4;
    __shared__ float As[64 * 33];   // [i][o]
    __shared__ float Bs[32 * 64];   // [o][q]
    float acc[4][4];
    #pragma unroll
    for (int r = 0; r < 4; r++)
        #pragma unroll
        for (int c = 0; c < 4; c++) acc[r][c] = 0.f;
    for (int step = 0; step < 8; step++) {
        int ob = step * 32;
        __syncthreads();
        #pragma unroll
        for (int u = 0; u < 8; u++) {
            int idx = u * 256 + tid;
            int i = idx >> 5, o = idx & 31;
            As[i * 33 + o] = sfe_w2[((long)(k * 256 + it0 + i) << 8) + ob + o];
        }
        #pragma unroll
        for (int u = 0; u < 8; u++) {
            int idx = u * 256 + tid;
            int o = idx >> 6, q = idx & 63;
            Bs[o * 64 + q] = comb_w1[((long)(k * 256 + ob + o) << 8) + qt0 + q];
        }
        __syncthreads();
        #pragma unroll 4
        for (int o = 0; o < 32; o++) {
            const float4 bv = *(const float4*)&Bs[o * 64 + tq * 4];
            float a[4];
            #pragma unroll
            for (int r = 0; r < 4; r++) a[r] = As[(ti * 4 + r) * 33 + o];
            #pragma unroll
            for (int r = 0; r < 4; r++) {
                acc[r][0] += a[r] * bv.x;
                acc[r][1] += a[r] * bv.y;
                acc[r][2] += a[r] * bv.z;
                acc[r][3] += a[r] * bv.w;
            }
        }
    }
    ushort_t* dtp = (ushort_t*)(ws + OFF_DD);
    #pragma unroll
    for (int c = 0; c < 4; c++)
        #pragma unroll
        for (int r = 0; r < 4; r++)
            dtp[((k * 256 + qt0 + tq * 4 + c) << 8) + it0 + ti * 4 + r] = f2bf(acc[r][c]);
}

// ---- K6c: c1[b,k,:] = Fte_re@W1re + Fte_im@W1im + sfe_b1 ----
__global__ void k_prep_c1(const float* __restrict__ sfe_w1, const float* __restrict__ sfe_b1,
                          float* __restrict__ ws) {
    int k = blockIdx.x, b = blockIdx.y;
    int o = threadIdx.x;
    float acc = sfe_b1[k * 256 + o];
    const float* w1 = sfe_w1 + (long)k * 512 * 256;
    const float* fr = ws + OFF_FTR + (b * K_ + k) * D_;
    const float* fi = ws + OFF_FTI + (b * K_ + k) * D_;
    for (int c = 0; c < 256; c++)
        acc += fr[c] * w1[c * 256 + o] + fi[c] * w1[(256 + c) * 256 + o];
    ws[OFF_C1 + (b * K_ + k) * D_ + o] = acc;
}

// ---- K6d: bias_comb partial per k ----
__global__ void k_prep_bias(const float* __restrict__ sfe_b2, const float* __restrict__ comb_w1,
                            float* __restrict__ ws) {
    int k = blockIdx.x;
    int q = threadIdx.x;
    float acc = 0.f;
    for (int o = 0; o < 256; o++)
        acc += sfe_b2[k * 256 + o] * comb_w1[((k * 256 + o) << 8) + q];
    ws[OFF_BC + k * 256 + q] = acc;
}

// ---- K6e: W2ext bf16 [q2][288] = [comb_w2^T | in_proj_w^T/0.3 | 0] ----
__global__ void k_prep_w2(const float* __restrict__ comb_w2, const float* __restrict__ in_proj_w,
                          float* __restrict__ ws) {
    int q2 = blockIdx.x;
    ushort_t* w2e = (ushort_t*)(ws + OFF_W2E);
    for (int i = threadIdx.x; i < 288; i += 128) {
        float v = 0.f;
        if (i < 256) v = comb_w2[(i << 8) + q2];
        else if (i < 272) v = in_proj_w[((i - 256) << 8) + q2] * (1.0f / 0.3f);
        w2e[q2 * 288 + i] = f2bf(v);
    }
}

// ---- K7: Xhat (DFT of x over t, bf16 out) + att-weighted x (fp32) ----
__global__ void k_xhat(const float* __restrict__ x, float* __restrict__ ws) {
    int ntile = blockIdx.x, b = blockIdx.y;
    int tid = threadIdx.x;
    int n = ntile * 16 + (tid >> 4), c = tid & 15;
    __shared__ float ct[K_ * P_], st[K_ * P_], attl[P_];
    for (int i = tid; i < K_ * P_; i += 256) {
        int k = i / P_, t = i % P_;
        int r = (k * t) % P_;
        float ph = 6.283185307179586f * (float)r / (float)P_;
        ct[i] = cosf(ph);
        st[i] = sinf(ph);
    }
    if (tid < P_) attl[tid] = ws[OFF_ATT + b * P_ + tid];
    __syncthreads();
    float re[K_], im[K_], xwa = 0.f;
    #pragma unroll
    for (int k = 0; k < K_; k++) { re[k] = 0.f; im[k] = 0.f; }
    for (int t = 0; t < P_; t++) {
        float v = x[((long)(b * P_ + t) * N_ + n) * C_ + c];
        xwa += attl[t] * v;
        #pragma unroll
        for (int k = 0; k < K_; k++) {
            re[k] += ct[k * P_ + t] * v;
            im[k] -= st[k * P_ + t] * v;
        }
    }
    ushort_t* xcp = (ushort_t*)(ws + OFF_XC);
    #pragma unroll
    for (int k = 0; k < K_; k++) {
        long xb = ((long)(b * K_ + k) * N_ + n) * 32;
        xcp[xb + c] = f2bf(re[k]);
        xcp[xb + 16 + c] = f2bf(im[k]);
    }
    ws[OFF_XW + ((long)b * N_ + n) * C_ + c] = xwa;
}

// ---- K9: fused p1-MFMA -> GEMM1 -> gelu -> GEMM2 -> z ----
__global__ __launch_bounds__(512) void k_final(
        const float* __restrict__ ws, const ushort_t* __restrict__ xch,
        const ushort_t* __restrict__ abt,
        const float* __restrict__ comb_b1, const float* __restrict__ comb_b2,
        float* __restrict__ out) {
    int ntile = blockIdx.x, b = blockIdx.y;
    int n0 = ntile * 32;
    int tid = threadIdx.x;
    int lane = tid & 63, wave = tid >> 6;
    int l15 = lane & 15, quad = lane >> 4;
    int wq0 = wave * 32;
    __shared__ ushort_t sh[32 * 296];
    const ushort_t* dt = (const ushort_t*)(ws + OFF_DD);
    const ushort_t* w2e = (const ushort_t*)(ws + OFF_W2E);

    f32x4 acc00 = {}, acc01 = {}, acc10 = {}, acc11 = {};
    for (int k = 0; k < K_; k++) {
        // p1 strip via MFMA (K=32): A = Xhat rows, B = ABt strip
        long xb = ((long)(b * K_ + k) * N_ + n0) * 32;
        bf16x8 pa0 = *(const bf16x8*)&xch[xb + l15 * 32 + quad * 8];
        bf16x8 pa1 = *(const bf16x8*)&xch[xb + (16 + l15) * 32 + quad * 8];
        const ushort_t* ab = abt + (k * 256 + wq0 + l15) * 32 + quad * 8;
        bf16x8 pb0 = *(const bf16x8*)ab;
        bf16x8 pb1 = *(const bf16x8*)(ab + 16 * 32);
        f32x4 p00 = {}, p01 = {}, p10 = {}, p11 = {};
        p00 = __builtin_amdgcn_mfma_f32_16x16x32_bf16(pa0, pb0, p00, 0, 0, 0);
        p01 = __builtin_amdgcn_mfma_f32_16x16x32_bf16(pa0, pb1, p01, 0, 0, 0);
        p10 = __builtin_amdgcn_mfma_f32_16x16x32_bf16(pa1, pb0, p10, 0, 0, 0);
        p11 = __builtin_amdgcn_mfma_f32_16x16x32_bf16(pa1, pb1, p11, 0, 0, 0);
        float c1a = ws[OFF_C1 + (b * K_ + k) * D_ + wq0 + l15];
        float c1b = ws[OFF_C1 + (b * K_ + k) * D_ + wq0 + 16 + l15];
        __syncthreads();   // previous GEMM1 reads complete before overwriting sh
        #pragma unroll
        for (int r = 0; r < 4; r++) {
            int na = quad * 4 + r, nb = 16 + quad * 4 + r;
            sh[na * 264 + wq0 + l15] = f2bf(gelu_f(p00[r] + c1a));
            sh[na * 264 + wq0 + 16 + l15] = f2bf(gelu_f(p01[r] + c1b));
            sh[nb * 264 + wq0 + l15] = f2bf(gelu_f(p10[r] + c1a));
            sh[nb * 264 + wq0 + 16 + l15] = f2bf(gelu_f(p11[r] + c1b));
        }
        __syncthreads();
        #pragma unroll
        for (int s = 0; s < 8; s++) {
            int i0 = s * 32;
            bf16x8 a0 = *(const bf16x8*)&sh[l15 * 264 + i0 + quad * 8];
            bf16x8 a1 = *(const bf16x8*)&sh[(16 + l15) * 264 + i0 + quad * 8];
            const ushort_t* db = dt + (((k * 256 + wq0 + l15) << 8) + i0 + quad * 8);
            bf16x8 b0 = *(const bf16x8*)db;
            bf16x8 b1 = *(const bf16x8*)(db + (16 << 8));
            acc00 = __builtin_amdgcn_mfma_f32_16x16x32_bf16(a0, b0, acc00, 0, 0, 0);
            acc01 = __builtin_amdgcn_mfma_f32_16x16x32_bf16(a0, b1, acc01, 0, 0, 0);
            acc10 = __builtin_amdgcn_mfma_f32_16x16x32_bf16(a1, b0, acc10, 0, 0, 0);
            acc11 = __builtin_amdgcn_mfma_f32_16x16x32_bf16(a1, b1, acc11, 0, 0, 0);
        }
    }
    __syncthreads();
    int q0 = wq0 + l15, q1 = wq0 + 16 + l15;
    float bc0 = comb_b1[q0], bc1 = comb_b1[q1];
    #pragma unroll
    for (int k = 0; k < K_; k++) {
        bc0 += ws[OFF_BC + k * 256 + q0];
        bc1 += ws[OFF_BC + k * 256 + q1];
    }
    #pragma unroll
    for (int r = 0; r < 4; r++) {
        int na = quad * 4 + r, nb = 16 + quad * 4 + r;
        sh[na * 296 + q0] = f2bf(gelu_f(acc00[r] + bc0));
        sh[na * 296 + q1] = f2bf(gelu_f(acc01[r] + bc1));
        sh[nb * 296 + q0] = f2bf(gelu_f(acc10[r] + bc0));
        sh[nb * 296 + q1] = f2bf(gelu_f(acc11[r] + bc1));
    }
    {
        int row = tid >> 4, cc = tid & 15;
        float xv = ws[OFF_XW + ((long)b * N_ + n0 + row) * C_ + cc];
        sh[row * 296 + 256 + cc] = f2bf(xv);
        sh[row * 296 + 272 + cc] = 0;
    }
    __syncthreads();
    f32x4 h00 = {}, h01 = {}, h10 = {}, h11 = {};
    #pragma unroll
    for (int s = 0; s < 9; s++) {
        int i0 = s * 32;
        bf16x8 a0 = *(const bf16x8*)&sh[l15 * 296 + i0 + quad * 8];
        bf16x8 a1 = *(const bf16x8*)&sh[(16 + l15) * 296 + i0 + quad * 8];
        const ushort_t* wb = w2e + ((wq0 + l15) * 288 + i0 + quad * 8);
        bf16x8 b0 = *(const bf16x8*)wb;
        bf16x8 b1 = *(const bf16x8*)(wb + 16 * 288);
        h00 = __builtin_amdgcn_mfma_f32_16x16x32_bf16(a0, b0, h00, 0, 0, 0);
        h01 = __builtin_amdgcn_mfma_f32_16x16x32_bf16(a0, b1, h01, 0, 0, 0);
        h10 = __builtin_amdgcn_mfma_f32_16x16x32_bf16(a1, b0, h10, 0, 0, 0);
        h11 = __builtin_amdgcn_mfma_f32_16x16x32_bf16(a1, b1, h11, 0, 0, 0);
    }
    float zc0 = ws[OFF_ZWC + b * 256 + q0], zc1 = ws[OFF_ZWC + b * 256 + q1];
    float cb0 = comb_b2[q0], cb1 = comb_b2[q1];
    long ob = ((long)b * N_ + n0) << 8;
    #pragma unroll
    for (int r = 0; r < 4; r++) {
        int na = quad * 4 + r, nb = 16 + quad * 4 + r;
        out[ob + ((long)na << 8) + q0] = zc0 + 0.3f * (h00[r] + cb0);
        out[ob + ((long)na << 8) + q1] = zc1 + 0.3f * (h01[r] + cb1);
        out[ob + ((long)nb << 8) + q0] = zc0 + 0.3f * (h10[r] + cb0);
        out[ob + ((long)nb << 8) + q1] = zc1 + 0.3f * (h11[r] + cb1);
    }
}

extern "C" void kernel_launch(void* const* d_in, const int* in_sizes, int n_in,
                              void* d_out, int out_size, void* d_ws, size_t ws_size,
                              hipStream_t stream) {
    const float* x = (const float*)d_in[0];
    const float* in_proj_w = (const float*)d_in[1];
    const float* in_proj_b = (const float*)d_in[2];
    const float* pe_w1 = (const float*)d_in[3];
    const float* pe_b1 = (const float*)d_in[4];
    const float* pe_w2 = (const float*)d_in[5];
    const float* pe_b2 = (const float*)d_in[6];
    const float* noise_w = (const float*)d_in[7];
    const float* noise_b = (const float*)d_in[8];
    const float* sfe_w1 = (const float*)d_in[9];
    const float* sfe_b1 = (const float*)d_in[10];
    const float* sfe_w2 = (const float*)d_in[11];
    const float* sfe_b2 = (const float*)d_in[12];
    const float* comb_w1 = (const float*)d_in[13];
    const float* comb_b1 = (const float*)d_in[14];
    const float* comb_w2 = (const float*)d_in[15];
    const float* comb_b2 = (const float*)d_in[16];
    const float* pool_param = (const float*)d_in[17];
    float* ws = (float*)d_ws;
    float* out = (float*)d_out;

    hipLaunchKernelGGL(k_spatial_mean, dim3(192), dim3(256), 0, stream, x, ws);
    hipLaunchKernelGGL(k_lag_dist, dim3(24, 4, 8), dim3(256), 0, stream, x, ws);
    hipLaunchKernelGGL(k_gating, dim3(8), dim3(128), 0, stream, pool_param, ws);
    hipLaunchKernelGGL(k_time_emb, dim3(192), dim3(128), 0, stream,
                       pe_w1, pe_b1, pe_w2, pe_b2, noise_w, noise_b, in_proj_b, ws);
    hipLaunchKernelGGL(k_te_reduce, dim3(8), dim3(256), 0, stream, in_proj_b, ws, out);
    hipLaunchKernelGGL(k_prep_ab, dim3(13), dim3(256), 0, stream, in_proj_w, sfe_w1, ws);
    hipLaunchKernelGGL(k_prep_d, dim3(4, 4, 13), dim3(256), 0, stream, sfe_w2, comb_w1, ws);
    hipLaunchKernelGGL(k_prep_bias, dim3(13), dim3(256), 0, stream, sfe_b2, comb_w1, ws);
    hipLaunchKernelGGL(k_prep_w2, dim3(256), dim3(128), 0, stream, comb_w2, in_proj_w, ws);
    hipLaunchKernelGGL(k_prep_c1, dim3(13, 8), dim3(256), 0, stream, sfe_w1, sfe_b1, ws);
    hipLaunchKernelGGL(k_xhat, dim3(64, 8), dim3(256), 0, stream, x, ws);
    hipLaunchKernelGGL(k_final, dim3(32, 8), dim3(512), 0, stream,
                       ws, (const ushort_t*)(ws + OFF_XC), (const ushort_t*)(ws + OFF_AB),
                       comb_b1, comb_b2, out);
}

// Round 5
// 333.357 us; speedup vs baseline: 3.2521x; 1.1677x over previous
//
#include <hip/hip_runtime.h>
#include <hip/hip_bf16.h>
#include <math.h>

#define B_ 8
#define P_ 24
#define N_ 1024
#define C_ 16
#define D_ 256
#define K_ 13

// workspace offsets (in floats)
#define OFF_SM   0          // spatial_mean: 192*16
#define OFF_DL   4096       // d_lag: 8*4*24
#define OFF_ATT  8192       // att: 8*24
#define OFF_TE   12288      // te_fold: 192*256
#define OFF_FTR  65536      // Fte_re: 8*13*256
#define OFF_FTI  94208      // Fte_im
#define OFF_ZWC  122880     // zw_const: 8*256
#define OFF_AB   126976     // ABt bf16 [k][o][32]: 13*256*32 ushorts
#define OFF_BC   266240     // bias_comb partials: 13*256
#define OFF_DD   270336     // Dt bf16 [k][q][i]: 13*256*256 ushorts
#define OFF_W2E  696320     // W2ext bf16 [q2][288]
#define OFF_XC   1126400    // Xhat bf16 [b][k][n][32]: 8*13*1024*32 ushorts
#define OFF_XW   2830336    // xw fp32: 8*1024*16
#define OFF_ABP  3000000    // AB partials fp32 [k][et][32ch][256o]: 13*8*32*256
#define OFF_C1P  3900000    // c1 partials fp32 [b][k][4][256]: 8*13*4*256

typedef unsigned short ushort_t;
typedef __bf16 bf16x8 __attribute__((ext_vector_type(8)));
typedef float f32x4 __attribute__((ext_vector_type(4)));

__device__ __forceinline__ float gelu_f(float v) {
    return 0.5f * v * (1.0f + erff(v * 0.70710678118654752440f));
}
__device__ __forceinline__ float softplus_f(float z) {
    return fmaxf(z, 0.0f) + log1pf(expf(-fabsf(z)));
}
__device__ __forceinline__ ushort_t f2bf(float f) {
    union { float f; unsigned u; } v; v.f = f;
    unsigned r = v.u + 0x7fffu + ((v.u >> 16) & 1u);
    return (ushort_t)(r >> 16);
}

// ---- K1: spatial mean of x over N per (b,t) ----
__global__ void k_spatial_mean(const float* __restrict__ x, float* __restrict__ ws) {
    int bt = blockIdx.x;
    int tid = threadIdx.x;
    int c = tid & 15, ns = tid >> 4;
    const float* xp = x + (long)bt * (N_ * C_);
    float s = 0.f;
    for (int n = ns; n < N_; n += 16) s += xp[n * C_ + c];
    __shared__ float lds[256];
    lds[tid] = s;
    __syncthreads();
    for (int st = 128; st >= 16; st >>= 1) {
        if (tid < st) lds[tid] += lds[tid + st];
        __syncthreads();
    }
    if (tid < 16) ws[OFF_SM + bt * 16 + tid] = lds[tid] * (1.0f / 1024.0f);
}

// ---- K2: lag distances, all 4 lags per (t,b) block ----
__global__ void k_lag_dist(const float* __restrict__ x, float* __restrict__ ws) {
    int t = blockIdx.x, b = blockIdx.y;
    int tid = threadIdx.x;  // 256
    const float* xp = x + (long)b * P_ * N_ * C_;
    float s1 = 0.f, s2 = 0.f, s4 = 0.f, s6 = 0.f;
    for (int idx = tid; idx < N_ * C_; idx += 256) {
        float xv[9];
        #pragma unroll
        for (int j = 0; j < 9; j++)
            xv[j] = (t - j >= 0) ? xp[(long)(t - j) * (N_ * C_) + idx] : 0.f;
        // xr at time t-j from xv[j], xv[j+1], xv[j+2]
        float xr[7];
        #pragma unroll
        for (int j = 0; j < 7; j++) {
            int s = t - j;
            float xt = xv[j];
            xr[j] = (s <= 0) ? 0.f
                  : (s == 1) ? (xt - xv[j + 1])
                  : (xt - (xt + xv[j + 1] + xv[j + 2]) * (1.0f / 3.0f));
        }
        if (t >= 1) s1 += fabsf(xr[0] - xr[1]);
        if (t >= 2) s2 += fabsf(xr[0] - xr[2]);
        if (t >= 4) s4 += fabsf(xr[0] - xr[4]);
        if (t >= 6) s6 += fabsf(xr[0] - xr[6]);
    }
    __shared__ float4 red[256];
    red[tid] = make_float4(s1, s2, s4, s6);
    __syncthreads();
    for (int st = 128; st > 0; st >>= 1) {
        if (tid < st) {
            red[tid].x += red[tid + st].x;
            red[tid].y += red[tid + st].y;
            red[tid].z += red[tid + st].z;
            red[tid].w += red[tid + st].w;
        }
        __syncthreads();
    }
    if (tid == 0) {
        const float inv = 1.0f / (N_ * C_);
        ws[OFF_DL + (b * 4 + 0) * P_ + t] = red[0].x * inv;
        ws[OFF_DL + (b * 4 + 1) * P_ + t] = red[0].y * inv;
        ws[OFF_DL + (b * 4 + 2) * P_ + t] = red[0].z * inv;
        ws[OFF_DL + (b * 4 + 3) * P_ + t] = red[0].w * inv;
    }
}

// ---- K3: gating -> att  (rank-select median, all-LDS) ----
__global__ void k_gating(const float* __restrict__ pool_param, float* __restrict__ ws) {
    int b = blockIdx.x;
    int tid = threadIdx.x;  // 128
    int li = tid / P_, t = tid - li * P_;
    bool active = tid < 4 * P_;
    __shared__ float d[4][P_], ad[4][P_], med[4], mad[4], g[P_], gbuf[P_];
    if (active) d[li][t] = ws[OFF_DL + (b * 4 + li) * P_ + t];
    __syncthreads();
    if (active) {
        float v = d[li][t];
        int rank = 0;
        #pragma unroll
        for (int j = 0; j < P_; j++) {
            float dj = d[li][j];
            rank += (dj < v || (dj == v && j < t)) ? 1 : 0;
        }
        if (rank == 11) med[li] = v;
    }
    __syncthreads();
    if (active) ad[li][t] = fabsf(d[li][t] - med[li]);
    __syncthreads();
    if (active) {
        float v = ad[li][t];
        int rank = 0;
        #pragma unroll
        for (int j = 0; j < P_; j++) {
            float dj = ad[li][j];
            rank += (dj < v || (dj == v && j < t)) ? 1 : 0;
        }
        if (rank == 11) mad[li] = v;
    }
    __syncthreads();
    if (active) {
        float z = (d[li][t] - med[li]) / (mad[li] * 1.4826f + 1e-6f);
        ad[li][t] = softplus_f(z);
    }
    __syncthreads();
    if (tid < P_) g[tid] = 0.25f * (ad[0][tid] + ad[1][tid] + ad[2][tid] + ad[3][tid]);
    __syncthreads();
    if (tid == 0) {
        float c = g[0];
        gbuf[0] = g[0];
        for (int tt = 1; tt < P_; tt++) { c = 0.6f * c + 0.4f * g[tt]; gbuf[tt] = c; }
        float mean = 0.f;
        for (int tt = 0; tt < P_; tt++) mean += gbuf[tt];
        mean *= (1.0f / P_);
        float gate[P_];
        #pragma unroll
        for (int tt = 0; tt < P_; tt++) gate[tt] = 1.0f / (1.0f + expf(-1.5f * (gbuf[tt] - mean)));
        float m = -1e30f;
        float pp[P_];
        #pragma unroll
        for (int tt = 0; tt < P_; tt++) { pp[tt] = pool_param[tt]; m = fmaxf(m, pp[tt]); }
        float ssum = 0.f;
        #pragma unroll
        for (int tt = 0; tt < P_; tt++) { pp[tt] = expf(pp[tt] - m); ssum += pp[tt]; }
        float m2 = -1e30f;
        #pragma unroll
        for (int tt = 0; tt < P_; tt++) { pp[tt] = (pp[tt] / ssum) * (1.0f + gate[tt]); m2 = fmaxf(m2, pp[tt]); }
        float s2 = 0.f;
        #pragma unroll
        for (int tt = 0; tt < P_; tt++) { pp[tt] = expf(pp[tt] - m2); s2 += pp[tt]; }
        #pragma unroll
        for (int tt = 0; tt < P_; tt++) ws[OFF_ATT + b * P_ + tt] = pp[tt] / s2;
    }
}

// ---- K4: time_emb (+ in_proj_b folded) ----
__global__ void k_time_emb(const float* __restrict__ pe_w1, const float* __restrict__ pe_b1,
                           const float* __restrict__ pe_w2, const float* __restrict__ pe_b2,
                           const float* __restrict__ noise_w, const float* __restrict__ noise_b,
                           const float* __restrict__ in_proj_b, float* __restrict__ ws) {
    int bt = blockIdx.x;
    int t = bt % P_;
    int tid = threadIdx.x;  // 128
    int k = tid >> 6, o = tid & 63;
    __shared__ float p1e[128];
    float period = (k == 0) ? 24.0f : 72.0f;
    float ph = 6.283185307179586f * (float)t / period;
    float sv = sinf(ph), cv = cosf(ph);
    float v = sv * pe_w1[(k * 2 + 0) * 64 + o] + cv * pe_w1[(k * 2 + 1) * 64 + o] + pe_b1[k * 64 + o];
    p1e[tid] = gelu_f(v);
    __syncthreads();
    float acc = pe_b2[k * 64 + o];
    for (int i = 0; i < 64; i++) acc += p1e[k * 64 + i] * pe_w2[(k * 64 + i) * 64 + o];
    ws[OFF_TE + bt * D_ + tid] = acc + in_proj_b[tid];
    float nacc = noise_b[tid];
    for (int c = 0; c < C_; c++) nacc += ws[OFF_SM + bt * C_ + c] * noise_w[c * 128 + tid];
    ws[OFF_TE + bt * D_ + 128 + tid] = nacc + in_proj_b[128 + tid];
}

// ---- K5: DFT of te_fold, att-weighted te, time_vec ----
__global__ void k_te_reduce(const float* __restrict__ in_proj_b, float* __restrict__ ws,
                            float* __restrict__ out) {
    int b = blockIdx.x;
    int tid = threadIdx.x;  // 256 = channel
    __shared__ float ct[K_ * P_], st[K_ * P_], attl[P_];
    for (int i = tid; i < K_ * P_; i += 256) {
        int k = i / P_, t = i % P_;
        int r = (k * t) % P_;
        float ph = 6.283185307179586f * (float)r / (float)P_;
        ct[i] = cosf(ph);
        st[i] = sinf(ph);
    }
    if (tid < P_) attl[tid] = ws[OFF_ATT + b * P_ + tid];
    __syncthreads();
    float fre[K_], fim[K_];
    #pragma unroll
    for (int k = 0; k < K_; k++) { fre[k] = 0.f; fim[k] = 0.f; }
    float sm = 0.f, sa = 0.f;
    for (int t = 0; t < P_; t++) {
        float v = ws[OFF_TE + (b * P_ + t) * D_ + tid];
        sm += v;
        sa += attl[t] * v;
        #pragma unroll
        for (int k = 0; k < K_; k++) {
            fre[k] += ct[k * P_ + t] * v;
            fim[k] -= st[k * P_ + t] * v;
        }
    }
    out[2097152 + b * D_ + tid] = sm * (1.0f / P_) - in_proj_b[tid];
    ws[OFF_ZWC + b * D_ + tid] = sa;
    #pragma unroll
    for (int k = 0; k < K_; k++) {
        ws[OFF_FTR + (b * K_ + k) * D_ + tid] = fre[k];
        ws[OFF_FTI + (b * K_ + k) * D_ + tid] = fim[k];
    }
}

// ---- K6a-1: AB partials over e-chunks: [k][et][32ch][256o] fp32 ----
__global__ void k_prep_ab_part(const float* __restrict__ in_proj_w,
                               const float* __restrict__ sfe_w1, float* __restrict__ ws) {
    int k = blockIdx.x, et = blockIdx.y;  // 13 x 8
    int o = threadIdx.x;
    float accA[C_], accB[C_];
    #pragma unroll
    for (int c = 0; c < C_; c++) { accA[c] = 0.f; accB[c] = 0.f; }
    const float* w1r = sfe_w1 + (long)k * 512 * 256;
    const float* w1i = w1r + 256 * 256;
    for (int e = et * 32; e < et * 32 + 32; e++) {
        float vr = w1r[e * 256 + o];
        float vi = w1i[e * 256 + o];
        #pragma unroll
        for (int c = 0; c < C_; c++) {
            float w = in_proj_w[c * 256 + e];  // wave-uniform -> scalar load
            accA[c] += w * vr;
            accB[c] += w * vi;
        }
    }
    float* abp = ws + OFF_ABP + (long)((k * 8 + et) * 32) * 256;
    #pragma unroll
    for (int c = 0; c < C_; c++) {
        abp[c * 256 + o] = accA[c];
        abp[(16 + c) * 256 + o] = accB[c];
    }
}

// ---- K6a-2: reduce AB partials -> ABt bf16 [k][o][32] ----
__global__ void k_prep_ab_red(float* __restrict__ ws) {
    int k = blockIdx.x;
    int o = threadIdx.x;
    ushort_t* abt = (ushort_t*)(ws + OFF_AB);
    const float* base = ws + OFF_ABP + (long)(k * 8 * 32) * 256;
    #pragma unroll
    for (int ch = 0; ch < 32; ch++) {
        float s = 0.f;
        #pragma unroll
        for (int et = 0; et < 8; et++) s += base[(et * 32 + ch) * 256 + o];
        abt[(k * 256 + o) * 32 + ch] = f2bf(s);
    }
}

// ---- K6b: Dt[k][q][i] bf16 (LDS-tiled) + bias_comb fold (it0==0 blocks) ----
__global__ void k_prep_d(const float* __restrict__ sfe_w2, const float* __restrict__ comb_w1,
                         const float* __restrict__ sfe_b2, float* __restrict__ ws) {
    int qt0 = blockIdx.x * 64, it0 = blockIdx.y * 64, k = blockIdx.z;
    int tid = threadIdx.x;
    int tq = tid & 15, ti = tid >> 4;
    __shared__ float As[64 * 33];   // [i][o]
    __shared__ float Bs[32 * 64];   // [o][q]
    float acc[4][4];
    #pragma unroll
    for (int r = 0; r < 4; r++)
        #pragma unroll
        for (int c = 0; c < 4; c++) acc[r][c] = 0.f;
    float bias = 0.f;
    for (int step = 0; step < 8; step++) {
        int ob = step * 32;
        __syncthreads();
        #pragma unroll
        for (int u = 0; u < 8; u++) {
            int idx = u * 256 + tid;
            int i = idx >> 5, o = idx & 31;
            As[i * 33 + o] = sfe_w2[((long)(k * 256 + it0 + i) << 8) + ob + o];
        }
        #pragma unroll
        for (int u = 0; u < 8; u++) {
            int idx = u * 256 + tid;
            int o = idx >> 6, q = idx & 63;
            Bs[o * 64 + q] = comb_w1[((long)(k * 256 + ob + o) << 8) + qt0 + q];
        }
        __syncthreads();
        if (blockIdx.y == 0 && tid < 64) {
            #pragma unroll
            for (int o = 0; o < 32; o++)
                bias += sfe_b2[k * 256 + ob + o] * Bs[o * 64 + tid];
        }
        #pragma unroll 4
        for (int o = 0; o < 32; o++) {
            const float4 bv = *(const float4*)&Bs[o * 64 + tq * 4];
            float a[4];
            #pragma unroll
            for (int r = 0; r < 4; r++) a[r] = As[(ti * 4 + r) * 33 + o];
            #pragma unroll
            for (int r = 0; r < 4; r++) {
                acc[r][0] += a[r] * bv.x;
                acc[r][1] += a[r] * bv.y;
                acc[r][2] += a[r] * bv.z;
                acc[r][3] += a[r] * bv.w;
            }
        }
    }
    ushort_t* dtp = (ushort_t*)(ws + OFF_DD);
    #pragma unroll
    for (int c = 0; c < 4; c++)
        #pragma unroll
        for (int r = 0; r < 4; r++)
            dtp[((k * 256 + qt0 + tq * 4 + c) << 8) + it0 + ti * 4 + r] = f2bf(acc[r][c]);
    if (blockIdx.y == 0 && tid < 64)
        ws[OFF_BC + k * 256 + qt0 + tid] = bias;
}

// ---- K6c: c1 partials over K-chunks: [b][k][ec][256] ----
__global__ void k_prep_c1_part(const float* __restrict__ sfe_w1, float* __restrict__ ws) {
    int k = blockIdx.x, b = blockIdx.y, ec = blockIdx.z;  // 13 x 8 x 4
    int o = threadIdx.x;
    const float* w1 = sfe_w1 + (long)k * 512 * 256 + (long)ec * 128 * 256;
    const float* f = ws + ((ec < 2) ? OFF_FTR : OFF_FTI) + (b * K_ + k) * D_ + (ec & 1) * 128;
    float acc = 0.f;
    for (int c = 0; c < 128; c++)
        acc += f[c] * w1[c * 256 + o];
    ws[OFF_C1P + (long)((b * K_ + k) * 4 + ec) * 256 + o] = acc;
}

// ---- K6e: W2ext bf16 [q2][288] = [comb_w2^T | in_proj_w^T/0.3 | 0] ----
__global__ void k_prep_w2(const float* __restrict__ comb_w2, const float* __restrict__ in_proj_w,
                          float* __restrict__ ws) {
    int q2 = blockIdx.x;
    ushort_t* w2e = (ushort_t*)(ws + OFF_W2E);
    for (int i = threadIdx.x; i < 288; i += 128) {
        float v = 0.f;
        if (i < 256) v = comb_w2[(i << 8) + q2];
        else if (i < 272) v = in_proj_w[((i - 256) << 8) + q2] * (1.0f / 0.3f);
        w2e[q2 * 288 + i] = f2bf(v);
    }
}

// ---- K7: Xhat (DFT of x over t, bf16 out) + att-weighted x (fp32) ----
__global__ void k_xhat(const float* __restrict__ x, float* __restrict__ ws) {
    int ntile = blockIdx.x, b = blockIdx.y;
    int tid = threadIdx.x;
    int n = ntile * 16 + (tid >> 4), c = tid & 15;
    __shared__ float ct[K_ * P_], st[K_ * P_], attl[P_];
    for (int i = tid; i < K_ * P_; i += 256) {
        int k = i / P_, t = i % P_;
        int r = (k * t) % P_;
        float ph = 6.283185307179586f * (float)r / (float)P_;
        ct[i] = cosf(ph);
        st[i] = sinf(ph);
    }
    if (tid < P_) attl[tid] = ws[OFF_ATT + b * P_ + tid];
    __syncthreads();
    float re[K_], im[K_], xwa = 0.f;
    #pragma unroll
    for (int k = 0; k < K_; k++) { re[k] = 0.f; im[k] = 0.f; }
    for (int t = 0; t < P_; t++) {
        float v = x[((long)(b * P_ + t) * N_ + n) * C_ + c];
        xwa += attl[t] * v;
        #pragma unroll
        for (int k = 0; k < K_; k++) {
            re[k] += ct[k * P_ + t] * v;
            im[k] -= st[k * P_ + t] * v;
        }
    }
    ushort_t* xcp = (ushort_t*)(ws + OFF_XC);
    #pragma unroll
    for (int k = 0; k < K_; k++) {
        long xb = ((long)(b * K_ + k) * N_ + n) * 32;
        xcp[xb + c] = f2bf(re[k]);
        xcp[xb + 16 + c] = f2bf(im[k]);
    }
    ws[OFF_XW + ((long)b * N_ + n) * C_ + c] = xwa;
}

// ---- K9: fused p1-MFMA -> GEMM1 -> gelu -> GEMM2 -> z ----
// 512 thr = 8 waves; tile 32n x 256q; dbuf p1 slab => 1 barrier per k
__global__ __launch_bounds__(512, 2) void k_final(
        const float* __restrict__ ws, const ushort_t* __restrict__ xch,
        const ushort_t* __restrict__ abt, const float* __restrict__ sfe_b1,
        const float* __restrict__ comb_b1, const float* __restrict__ comb_b2,
        float* __restrict__ out) {
    int ntile = blockIdx.x, b = blockIdx.y;  // 32 x 8
    int n0 = ntile * 32;
    int tid = threadIdx.x;
    int lane = tid & 63, wave = tid >> 6;
    int l15 = lane & 15, quad = lane >> 4;
    int wq0 = wave * 32;
    int q0 = wq0 + l15, q1 = wq0 + 16 + l15;
    __shared__ ushort_t slab[2][32 * 264];
    __shared__ ushort_t sh2[32 * 296];
    const ushort_t* dt = (const ushort_t*)(ws + OFF_DD);
    const ushort_t* w2e = (const ushort_t*)(ws + OFF_W2E);

    f32x4 acc00 = {}, acc01 = {}, acc10 = {}, acc11 = {};
    // prefetch k=0 p1 inputs
    long xb = ((long)(b * K_) * N_ + n0) * 32;
    bf16x8 pa0 = *(const bf16x8*)&xch[xb + l15 * 32 + quad * 8];
    bf16x8 pa1 = *(const bf16x8*)&xch[xb + (16 + l15) * 32 + quad * 8];
    const ushort_t* ab = abt + (wq0 + l15) * 32 + quad * 8;
    bf16x8 pb0 = *(const bf16x8*)ab;
    bf16x8 pb1 = *(const bf16x8*)(ab + 16 * 32);

    for (int k = 0; k < K_; k++) {
        // GEMM1 B-frags for this k: independent of slab -> issue before barrier
        bf16x8 Bf0[8], Bf1[8];
        const ushort_t* db = dt + ((long)(k * 256 + q0) << 8) + quad * 8;
        #pragma unroll
        for (int s = 0; s < 8; s++) {
            Bf0[s] = *(const bf16x8*)(db + s * 32);
            Bf1[s] = *(const bf16x8*)(db + (16 << 8) + s * 32);
        }
        // p1 strip via MFMA
        f32x4 p00 = {}, p01 = {}, p10 = {}, p11 = {};
        p00 = __builtin_amdgcn_mfma_f32_16x16x32_bf16(pa0, pb0, p00, 0, 0, 0);
        p01 = __builtin_amdgcn_mfma_f32_16x16x32_bf16(pa0, pb1, p01, 0, 0, 0);
        p10 = __builtin_amdgcn_mfma_f32_16x16x32_bf16(pa1, pb0, p10, 0, 0, 0);
        p11 = __builtin_amdgcn_mfma_f32_16x16x32_bf16(pa1, pb1, p11, 0, 0, 0);
        // c1 = sfe_b1 + 4 partials
        float c1a = sfe_b1[k * 256 + q0], c1b = sfe_b1[k * 256 + q1];
        #pragma unroll
        for (int ec = 0; ec < 4; ec++) {
            const float* cp = ws + OFF_C1P + (long)((b * K_ + k) * 4 + ec) * 256;
            c1a += cp[q0];
            c1b += cp[q1];
        }
        ushort_t* sl = slab[k & 1];
        #pragma unroll
        for (int r = 0; r < 4; r++) {
            int na = quad * 4 + r, nb = 16 + quad * 4 + r;
            sl[na * 264 + q0] = f2bf(gelu_f(p00[r] + c1a));
            sl[na * 264 + q1] = f2bf(gelu_f(p01[r] + c1b));
            sl[nb * 264 + q0] = f2bf(gelu_f(p10[r] + c1a));
            sl[nb * 264 + q1] = f2bf(gelu_f(p11[r] + c1b));
        }
        // prefetch k+1 p1 inputs
        if (k + 1 < K_) {
            xb = ((long)(b * K_ + k + 1) * N_ + n0) * 32;
            pa0 = *(const bf16x8*)&xch[xb + l15 * 32 + quad * 8];
            pa1 = *(const bf16x8*)&xch[xb + (16 + l15) * 32 + quad * 8];
            ab = abt + ((k + 1) * 256 + wq0 + l15) * 32 + quad * 8;
            pb0 = *(const bf16x8*)ab;
            pb1 = *(const bf16x8*)(ab + 16 * 32);
        }
        __syncthreads();
        #pragma unroll
        for (int s = 0; s < 8; s++) {
            int i0 = s * 32;
            bf16x8 a0 = *(const bf16x8*)&sl[l15 * 264 + i0 + quad * 8];
            bf16x8 a1 = *(const bf16x8*)&sl[(16 + l15) * 264 + i0 + quad * 8];
            acc00 = __builtin_amdgcn_mfma_f32_16x16x32_bf16(a0, Bf0[s], acc00, 0, 0, 0);
            acc01 = __builtin_amdgcn_mfma_f32_16x16x32_bf16(a0, Bf1[s], acc01, 0, 0, 0);
            acc10 = __builtin_amdgcn_mfma_f32_16x16x32_bf16(a1, Bf0[s], acc10, 0, 0, 0);
            acc11 = __builtin_amdgcn_mfma_f32_16x16x32_bf16(a1, Bf1[s], acc11, 0, 0, 0);
        }
    }
    __syncthreads();
    // bias + gelu -> Uext bf16
    float bc0 = comb_b1[q0], bc1 = comb_b1[q1];
    #pragma unroll
    for (int k = 0; k < K_; k++) {
        bc0 += ws[OFF_BC + k * 256 + q0];
        bc1 += ws[OFF_BC + k * 256 + q1];
    }
    #pragma unroll
    for (int r = 0; r < 4; r++) {
        int na = quad * 4 + r, nb = 16 + quad * 4 + r;
        sh2[na * 296 + q0] = f2bf(gelu_f(acc00[r] + bc0));
        sh2[na * 296 + q1] = f2bf(gelu_f(acc01[r] + bc1));
        sh2[nb * 296 + q0] = f2bf(gelu_f(acc10[r] + bc0));
        sh2[nb * 296 + q1] = f2bf(gelu_f(acc11[r] + bc1));
    }
    {
        int row = tid >> 4, cc = tid & 15;  // 32 rows x 16 c
        float xv = ws[OFF_XW + ((long)b * N_ + n0 + row) * C_ + cc];
        sh2[row * 296 + 256 + cc] = f2bf(xv);
        sh2[row * 296 + 272 + cc] = 0;
    }
    __syncthreads();
    f32x4 h00 = {}, h01 = {}, h10 = {}, h11 = {};
    #pragma unroll
    for (int s = 0; s < 9; s++) {
        int i0 = s * 32;
        bf16x8 a0 = *(const bf16x8*)&sh2[l15 * 296 + i0 + quad * 8];
        bf16x8 a1 = *(const bf16x8*)&sh2[(16 + l15) * 296 + i0 + quad * 8];
        const ushort_t* wb = w2e + ((wq0 + l15) * 288 + i0 + quad * 8);
        bf16x8 b0 = *(const bf16x8*)wb;
        bf16x8 b1 = *(const bf16x8*)(wb + 16 * 288);
        h00 = __builtin_amdgcn_mfma_f32_16x16x32_bf16(a0, b0, h00, 0, 0, 0);
        h01 = __builtin_amdgcn_mfma_f32_16x16x32_bf16(a0, b1, h01, 0, 0, 0);
        h10 = __builtin_amdgcn_mfma_f32_16x16x32_bf16(a1, b0, h10, 0, 0, 0);
        h11 = __builtin_amdgcn_mfma_f32_16x16x32_bf16(a1, b1, h11, 0, 0, 0);
    }
    float zc0 = ws[OFF_ZWC + b * 256 + q0], zc1 = ws[OFF_ZWC + b * 256 + q1];
    float cb0 = comb_b2[q0], cb1 = comb_b2[q1];
    long ob = ((long)b * N_ + n0) << 8;
    #pragma unroll
    for (int r = 0; r < 4; r++) {
        int na = quad * 4 + r, nb = 16 + quad * 4 + r;
        out[ob + ((long)na << 8) + q0] = zc0 + 0.3f * (h00[r] + cb0);
        out[ob + ((long)na << 8) + q1] = zc1 + 0.3f * (h01[r] + cb1);
        out[ob + ((long)nb << 8) + q0] = zc0 + 0.3f * (h10[r] + cb0);
        out[ob + ((long)nb << 8) + q1] = zc1 + 0.3f * (h11[r] + cb1);
    }
}

extern "C" void kernel_launch(void* const* d_in, const int* in_sizes, int n_in,
                              void* d_out, int out_size, void* d_ws, size_t ws_size,
                              hipStream_t stream) {
    const float* x = (const float*)d_in[0];
    const float* in_proj_w = (const float*)d_in[1];
    const float* in_proj_b = (const float*)d_in[2];
    const float* pe_w1 = (const float*)d_in[3];
    const float* pe_b1 = (const float*)d_in[4];
    const float* pe_w2 = (const float*)d_in[5];
    const float* pe_b2 = (const float*)d_in[6];
    const float* noise_w = (const float*)d_in[7];
    const float* noise_b = (const float*)d_in[8];
    const float* sfe_w1 = (const float*)d_in[9];
    const float* sfe_b1 = (const float*)d_in[10];
    const float* sfe_w2 = (const float*)d_in[11];
    const float* sfe_b2 = (const float*)d_in[12];
    const float* comb_w1 = (const float*)d_in[13];
    const float* comb_b1 = (const float*)d_in[14];
    const float* comb_w2 = (const float*)d_in[15];
    const float* comb_b2 = (const float*)d_in[16];
    const float* pool_param = (const float*)d_in[17];
    float* ws = (float*)d_ws;
    float* out = (float*)d_out;

    hipLaunchKernelGGL(k_spatial_mean, dim3(192), dim3(256), 0, stream, x, ws);
    hipLaunchKernelGGL(k_lag_dist, dim3(24, 8), dim3(256), 0, stream, x, ws);
    hipLaunchKernelGGL(k_gating, dim3(8), dim3(128), 0, stream, pool_param, ws);
    hipLaunchKernelGGL(k_time_emb, dim3(192), dim3(128), 0, stream,
                       pe_w1, pe_b1, pe_w2, pe_b2, noise_w, noise_b, in_proj_b, ws);
    hipLaunchKernelGGL(k_te_reduce, dim3(8), dim3(256), 0, stream, in_proj_b, ws, out);
    hipLaunchKernelGGL(k_prep_ab_part, dim3(13, 8), dim3(256), 0, stream, in_proj_w, sfe_w1, ws);
    hipLaunchKernelGGL(k_prep_ab_red, dim3(13), dim3(256), 0, stream, ws);
    hipLaunchKernelGGL(k_prep_d, dim3(4, 4, 13), dim3(256), 0, stream, sfe_w2, comb_w1, sfe_b2, ws);
    hipLaunchKernelGGL(k_prep_w2, dim3(256), dim3(128), 0, stream, comb_w2, in_proj_w, ws);
    hipLaunchKernelGGL(k_prep_c1_part, dim3(13, 8, 4), dim3(256), 0, stream, sfe_w1, ws);
    hipLaunchKernelGGL(k_xhat, dim3(64, 8), dim3(256), 0, stream, x, ws);
    hipLaunchKernelGGL(k_final, dim3(32, 8), dim3(512), 0, stream,
                       ws, (const ushort_t*)(ws + OFF_XC), (const ushort_t*)(ws + OFF_AB),
                       sfe_b1, comb_b1, comb_b2, out);
}